// Round 1
// baseline (2000.096 us; speedup 1.0000x reference)
//
#include <hip/hip_runtime.h>
#include <cstdint>
#include <cstddef>

#define NB   8
#define NPTS 4096
#define KNN  20

// ---------------------------------------------------------------------------
// ordered-float transform: monotone fp32 -> uint32 (no NaNs present)
__device__ __forceinline__ uint32_t f2ord(float v) {
    uint32_t u = __float_as_uint(v);
    return (u & 0x80000000u) ? ~u : (u | 0x80000000u);
}

__device__ __forceinline__ unsigned long long shfl_down_u64(unsigned long long v, int off) {
    uint32_t lo = (uint32_t)v, hi = (uint32_t)(v >> 32);
    lo = (uint32_t)__shfl_down((int)lo, off, 64);
    hi = (uint32_t)__shfl_down((int)hi, off, 64);
    return ((unsigned long long)hi << 32) | lo;
}

__device__ __forceinline__ unsigned long long shfl_u64(unsigned long long v, int lane) {
    uint32_t lo = (uint32_t)v, hi = (uint32_t)(v >> 32);
    lo = (uint32_t)__shfl((int)lo, lane, 64);
    hi = (uint32_t)__shfl((int)hi, lane, 64);
    return ((unsigned long long)hi << 32) | lo;
}

// ---------------------------------------------------------------------------
// Kernel 1: per-point top-20 neighbor selection (pair = -||xn - xm||^2 via
// 2ab - a^2 - b^2, matching the reference formula; ties -> lower index).
// One wave (64 lanes) per (b, n). Lane l owns columns m with m%64 == l.
__global__ __launch_bounds__(64) void topk_kernel(
    const float* __restrict__ x,   // (B,3,N)
    int*   __restrict__ idx_out,   // (B,N,K)
    float* __restrict__ dist_out)  // (B,N,K)
{
    const int n = blockIdx.x;
    const int b = blockIdx.y;
    const int l = threadIdx.x;
    __shared__ uint32_t s_val[NPTS];

    const float* xb = x + (size_t)b * 3 * NPTS;
    const float xn0 = xb[n], xn1 = xb[NPTS + n], xn2 = xb[2 * NPTS + n];
    const float sqn = fmaf(xn2, xn2, fmaf(xn1, xn1, xn0 * xn0));

    unsigned long long bk = 0ull;  // lane-local best key over unconsumed cols
    for (int j = 0; j < NPTS / 64; ++j) {
        const int m = j * 64 + l;                       // coalesced
        const float m0 = xb[m], m1 = xb[NPTS + m], m2 = xb[2 * NPTS + m];
        const float dot = fmaf(xn2, m2, fmaf(xn1, m1, xn0 * m0));
        const float sqm = fmaf(m2, m2, fmaf(m1, m1, m0 * m0));
        const float pair = 2.0f * dot - sqn - sqm;
        const uint32_t u = f2ord(pair);
        s_val[m] = u;
        const unsigned long long key =
            ((unsigned long long)u << 32) | (uint32_t)(NPTS - 1 - m);
        bk = key > bk ? key : bk;
    }
    // s_val columns are lane-private (written & re-read only by owner lane);
    // cross-lane communication is via shuffles only -> no barrier needed.

    int my_m = 0;  // lane k holds round-k winner afterwards
    for (int k = 0; k < KNN; ++k) {
        unsigned long long r = bk;
        #pragma unroll
        for (int off = 32; off >= 1; off >>= 1) {
            unsigned long long o = shfl_down_u64(r, off);
            r = o > r ? o : r;
        }
        r = shfl_u64(r, 0);  // broadcast winner key
        const int m = (NPTS - 1) - (int)(r & 0xFFFFFFFFu);
        if (l == k) my_m = m;
        if ((m & 63) == l) {       // owner removes winner, rescans its column
            s_val[m] = 0u;
            unsigned long long nb = 0ull;
            for (int j = 0; j < NPTS / 64; ++j) {
                const int mm = j * 64 + l;
                const unsigned long long key =
                    ((unsigned long long)s_val[mm] << 32) | (uint32_t)(NPTS - 1 - mm);
                nb = key > nb ? key : nb;
            }
            bk = nb;
        }
    }

    if (l < KNN) {
        const int m = my_m;
        const float m0 = xb[m], m1 = xb[NPTS + m], m2 = xb[2 * NPTS + m];
        const float d0 = m0 - xn0, d1 = m1 - xn1, d2 = m2 - xn2;
        const float dist = sqrtf(((d0 * d0 + d1 * d1) + d2 * d2) + 1e-12f);
        const size_t base = ((size_t)b * NPTS + n) * KNN + l;
        idx_out[base]  = m;
        dist_out[base] = dist;
    }
}

// ---------------------------------------------------------------------------
// tiny weight transpose: w (O,C) -> wt (C,O) so per-c reads are lane-coalesced
__global__ void transpose_w(const float* __restrict__ w, float* __restrict__ wt,
                            int O, int C) {
    int i = blockIdx.x * 256 + threadIdx.x;
    if (i < O * C) {
        int o = i / C, c = i - o * C;
        wt[c * O + o] = w[i];
    }
}

// ---------------------------------------------------------------------------
// Fused per-point MLP: feat(20x26) -> h1(20x64) -> h2(20x64) -> h3(20x128)
// -> h4(20x256), with per-layer relu and max-over-k into cat[512].
template <int O, int C>
__device__ __forceinline__ void conv_layer(
    const float* __restrict__ wt,  // (C, O) global, transposed
    const float* __restrict__ in,  // LDS [KNN][C]
    float* __restrict__ out,       // LDS [KNN][O]
    float* __restrict__ xmax)      // LDS [O]
{
    const int t = threadIdx.x;
    constexpr int KG  = 256 / O;   // 4, 4, 2, 1
    constexpr int KPT = KNN / KG;  // 5, 5, 10, 20
    const int o  = t % O;
    const int kg = t / O;
    float acc[KPT];
    #pragma unroll
    for (int i = 0; i < KPT; ++i) acc[i] = 0.f;

    if constexpr (C % 4 == 0) {
        for (int c = 0; c < C; c += 4) {
            const float w0 = wt[(c + 0) * O + o];
            const float w1 = wt[(c + 1) * O + o];
            const float w2 = wt[(c + 2) * O + o];
            const float w3 = wt[(c + 3) * O + o];
            #pragma unroll
            for (int i = 0; i < KPT; ++i) {
                const float4 v = *(const float4*)&in[(kg + i * KG) * C + c];
                acc[i] = fmaf(w0, v.x, acc[i]);
                acc[i] = fmaf(w1, v.y, acc[i]);
                acc[i] = fmaf(w2, v.z, acc[i]);
                acc[i] = fmaf(w3, v.w, acc[i]);
            }
        }
    } else {
        #pragma unroll 2
        for (int c = 0; c < C; ++c) {
            const float wv = wt[c * O + o];
            #pragma unroll
            for (int i = 0; i < KPT; ++i)
                acc[i] = fmaf(wv, in[(kg + i * KG) * C + c], acc[i]);
        }
    }
    #pragma unroll
    for (int i = 0; i < KPT; ++i) {
        const float v = acc[i] > 0.f ? acc[i] : 0.f;  // relu
        out[(kg + i * KG) * O + o] = v;
    }
    __syncthreads();
    if (t < O) {
        float mx = out[t];
        #pragma unroll
        for (int k = 1; k < KNN; ++k) mx = fmaxf(mx, out[k * O + t]);
        xmax[t] = mx;
    }
    __syncthreads();
}

__global__ __launch_bounds__(256) void fused_mlp(
    const float* __restrict__ x,        // (B,3,N)
    const int*   __restrict__ idx_ws,   // (B,N,K)
    const float* __restrict__ dist_ws,  // (B,N,K)
    const float* __restrict__ wt1,      // (26,64)
    const float* __restrict__ wt2,      // (64,64)
    const float* __restrict__ wt3,      // (64,128)
    const float* __restrict__ wt4,      // (128,256)
    float* __restrict__ cat_ws)         // (B*N, 512)
{
    const int n = blockIdx.x, b = blockIdx.y, t = threadIdx.x;
    __shared__ float s_feat[KNN * 26];
    __shared__ float s_X[KNN * 128];
    __shared__ float s_Y[KNN * 256];
    __shared__ float s_cat[512];

    const float* xb = x + (size_t)b * 3 * NPTS;
    const float xn0 = xb[n], xn1 = xb[NPTS + n], xn2 = xb[2 * NPTS + n];
    if (t < KNN) {
        const size_t base = ((size_t)b * NPTS + n) * KNN + t;
        const int m = idx_ws[base];
        const float d = dist_ws[base];
        const float m0 = xb[m], m1 = xb[NPTS + m], m2 = xb[2 * NPTS + m];
        float* fr = s_feat + t * 26;
        fr[0] = xn0; fr[1] = xn1; fr[2] = xn2;
        fr[3] = m0;  fr[4] = m1;  fr[5] = m2;
        #pragma unroll
        for (int k = 0; k < KNN; ++k) s_feat[k * 26 + 6 + t] = d;  // channel 6+t
    }
    __syncthreads();

    conv_layer<64, 26>(wt1, s_feat, s_X, s_cat);        // h1 in s_X[0:20*64]
    conv_layer<64, 64>(wt2, s_X, s_Y, s_cat + 64);      // h2 in s_Y[0:20*64]
    conv_layer<128, 64>(wt3, s_Y, s_X, s_cat + 128);    // h3 in s_X[0:20*128]
    conv_layer<256, 128>(wt4, s_X, s_Y, s_cat + 256);   // h4 in s_Y[0:20*256]

    float* dst = cat_ws + ((size_t)b * NPTS + n) * 512;
    for (int c = t; c < 512; c += 256) dst[c] = s_cat[c];
}

// ---------------------------------------------------------------------------
// Final GEMM: out[b,o,n] = relu( sum_c w5[o,c] * cat[b,n,c] ), 64x64 tile,
// 4x4 per thread, fp32.
__global__ __launch_bounds__(256) void final_gemm(
    const float* __restrict__ w5,   // (512,512)
    const float* __restrict__ cat,  // (B*N, 512)
    float* __restrict__ out)        // (B,512,N)
{
    const int b  = blockIdx.z;
    const int o0 = blockIdx.y * 64;
    const int n0 = blockIdx.x * 64;
    const int t  = threadIdx.x;
    const int tx = t & 15, ty = t >> 4;
    __shared__ float As[16][68];    // stride 68 floats = 272B (16B-aligned rows)
    __shared__ float Bs[16][68];
    float acc[4][4] = {{0.f, 0.f, 0.f, 0.f}, {0.f, 0.f, 0.f, 0.f},
                       {0.f, 0.f, 0.f, 0.f}, {0.f, 0.f, 0.f, 0.f}};
    const int lr = t >> 2;          // 0..63
    const int lc = (t & 3) * 4;     // 0,4,8,12
    const float* arow = w5 + (size_t)(o0 + lr) * 512;
    const float* brow = cat + ((size_t)b * NPTS + n0 + lr) * 512;

    for (int ck = 0; ck < 512; ck += 16) {
        const float4 av = *(const float4*)(arow + ck + lc);
        const float4 bv = *(const float4*)(brow + ck + lc);
        As[lc + 0][lr] = av.x; As[lc + 1][lr] = av.y;
        As[lc + 2][lr] = av.z; As[lc + 3][lr] = av.w;
        Bs[lc + 0][lr] = bv.x; Bs[lc + 1][lr] = bv.y;
        Bs[lc + 2][lr] = bv.z; Bs[lc + 3][lr] = bv.w;
        __syncthreads();
        #pragma unroll
        for (int c = 0; c < 16; ++c) {
            const float4 a  = *(const float4*)&As[c][ty * 4];
            const float4 bb = *(const float4*)&Bs[c][tx * 4];
            acc[0][0] = fmaf(a.x, bb.x, acc[0][0]);
            acc[0][1] = fmaf(a.x, bb.y, acc[0][1]);
            acc[0][2] = fmaf(a.x, bb.z, acc[0][2]);
            acc[0][3] = fmaf(a.x, bb.w, acc[0][3]);
            acc[1][0] = fmaf(a.y, bb.x, acc[1][0]);
            acc[1][1] = fmaf(a.y, bb.y, acc[1][1]);
            acc[1][2] = fmaf(a.y, bb.z, acc[1][2]);
            acc[1][3] = fmaf(a.y, bb.w, acc[1][3]);
            acc[2][0] = fmaf(a.z, bb.x, acc[2][0]);
            acc[2][1] = fmaf(a.z, bb.y, acc[2][1]);
            acc[2][2] = fmaf(a.z, bb.z, acc[2][2]);
            acc[2][3] = fmaf(a.z, bb.w, acc[2][3]);
            acc[3][0] = fmaf(a.w, bb.x, acc[3][0]);
            acc[3][1] = fmaf(a.w, bb.y, acc[3][1]);
            acc[3][2] = fmaf(a.w, bb.z, acc[3][2]);
            acc[3][3] = fmaf(a.w, bb.w, acc[3][3]);
        }
        __syncthreads();
    }
    #pragma unroll
    for (int i = 0; i < 4; ++i) {
        float4 v;
        v.x = fmaxf(acc[i][0], 0.f);
        v.y = fmaxf(acc[i][1], 0.f);
        v.z = fmaxf(acc[i][2], 0.f);
        v.w = fmaxf(acc[i][3], 0.f);
        *(float4*)&out[((size_t)b * 512 + o0 + ty * 4 + i) * NPTS + n0 + tx * 4] = v;
    }
}

// ---------------------------------------------------------------------------
extern "C" void kernel_launch(void* const* d_in, const int* in_sizes, int n_in,
                              void* d_out, int out_size, void* d_ws, size_t ws_size,
                              hipStream_t stream) {
    const float* x  = (const float*)d_in[0];  // (8,3,4096)
    const float* w1 = (const float*)d_in[1];  // (64,26)
    const float* w2 = (const float*)d_in[2];  // (64,64)
    const float* w3 = (const float*)d_in[3];  // (128,64)
    const float* w4 = (const float*)d_in[4];  // (256,128)
    const float* w5 = (const float*)d_in[5];  // (512,512)
    float* out = (float*)d_out;               // (8,512,4096) fp32

    // workspace layout (bytes):
    //   [0)            idx_ws   B*N*K int   = 2,621,440
    //   [2621440)      dist_ws  B*N*K f32   = 2,621,440
    //   [5242880)      cat_ws   B*N*512 f32 = 67,108,864
    //   [72351744)     wt1..wt4 transposed  =   186,880
    char* ws = (char*)d_ws;
    int*   idx_ws  = (int*)ws;
    float* dist_ws = (float*)(ws + 2621440);
    float* cat_ws  = (float*)(ws + 5242880);
    float* wt1     = (float*)(ws + 72351744);
    float* wt2     = wt1 + 26 * 64;
    float* wt3     = wt2 + 64 * 64;
    float* wt4     = wt3 + 64 * 128;

    transpose_w<<<dim3((64 * 26 + 255) / 256), 256, 0, stream>>>(w1, wt1, 64, 26);
    transpose_w<<<dim3((64 * 64 + 255) / 256), 256, 0, stream>>>(w2, wt2, 64, 64);
    transpose_w<<<dim3((128 * 64 + 255) / 256), 256, 0, stream>>>(w3, wt3, 128, 64);
    transpose_w<<<dim3((256 * 128 + 255) / 256), 256, 0, stream>>>(w4, wt4, 256, 128);

    topk_kernel<<<dim3(NPTS, NB), 64, 0, stream>>>(x, idx_ws, dist_ws);
    fused_mlp<<<dim3(NPTS, NB), 256, 0, stream>>>(x, idx_ws, dist_ws,
                                                  wt1, wt2, wt3, wt4, cat_ws);
    final_gemm<<<dim3(NPTS / 64, 512 / 64, NB), 256, 0, stream>>>(w5, cat_ws, out);
}

// Round 2
// 927.951 us; speedup vs baseline: 2.1554x; 2.1554x over previous
//
#include <hip/hip_runtime.h>
#include <cstdint>
#include <cstddef>

#define NB   8
#define NPTS 4096
#define KNN  20
#define P    4   // points per fused-MLP block (M = P*KNN = 80 rows = 5 m-tiles)

typedef __attribute__((ext_vector_type(8))) short  short8;
typedef __attribute__((ext_vector_type(4))) float  floatx4;

__device__ __forceinline__ uint16_t f2bf(float f) {
    uint32_t u = __float_as_uint(f);
    uint32_t r = (u + 0x7FFFu + ((u >> 16) & 1u)) >> 16;   // RNE
    return (uint16_t)r;
}
__device__ __forceinline__ float bf2f(uint16_t h) {
    return __uint_as_float(((uint32_t)h) << 16);
}

// ---------------------------------------------------------------------------
// ordered-float transform: monotone fp32 -> uint32 (no NaNs present)
__device__ __forceinline__ uint32_t f2ord(float v) {
    uint32_t u = __float_as_uint(v);
    return (u & 0x80000000u) ? ~u : (u | 0x80000000u);
}

__device__ __forceinline__ unsigned long long shfl_down_u64(unsigned long long v, int off) {
    uint32_t lo = (uint32_t)v, hi = (uint32_t)(v >> 32);
    lo = (uint32_t)__shfl_down((int)lo, off, 64);
    hi = (uint32_t)__shfl_down((int)hi, off, 64);
    return ((unsigned long long)hi << 32) | lo;
}
__device__ __forceinline__ unsigned long long shfl_u64(unsigned long long v, int lane) {
    uint32_t lo = (uint32_t)v, hi = (uint32_t)(v >> 32);
    lo = (uint32_t)__shfl((int)lo, lane, 64);
    hi = (uint32_t)__shfl((int)hi, lane, 64);
    return ((unsigned long long)hi << 32) | lo;
}

// ---------------------------------------------------------------------------
// Kernel 1: per-point top-20 neighbor selection (unchanged from round 1).
__global__ __launch_bounds__(64) void topk_kernel(
    const float* __restrict__ x,   // (B,3,N)
    int*   __restrict__ idx_out,   // (B,N,K)
    float* __restrict__ dist_out)  // (B,N,K)
{
    const int n = blockIdx.x;
    const int b = blockIdx.y;
    const int l = threadIdx.x;
    __shared__ uint32_t s_val[NPTS];

    const float* xb = x + (size_t)b * 3 * NPTS;
    const float xn0 = xb[n], xn1 = xb[NPTS + n], xn2 = xb[2 * NPTS + n];
    const float sqn = fmaf(xn2, xn2, fmaf(xn1, xn1, xn0 * xn0));

    unsigned long long bk = 0ull;
    for (int j = 0; j < NPTS / 64; ++j) {
        const int m = j * 64 + l;
        const float m0 = xb[m], m1 = xb[NPTS + m], m2 = xb[2 * NPTS + m];
        const float dot = fmaf(xn2, m2, fmaf(xn1, m1, xn0 * m0));
        const float sqm = fmaf(m2, m2, fmaf(m1, m1, m0 * m0));
        const float pair = 2.0f * dot - sqn - sqm;
        const uint32_t u = f2ord(pair);
        s_val[m] = u;
        const unsigned long long key =
            ((unsigned long long)u << 32) | (uint32_t)(NPTS - 1 - m);
        bk = key > bk ? key : bk;
    }

    int my_m = 0;
    for (int k = 0; k < KNN; ++k) {
        unsigned long long r = bk;
        #pragma unroll
        for (int off = 32; off >= 1; off >>= 1) {
            unsigned long long o = shfl_down_u64(r, off);
            r = o > r ? o : r;
        }
        r = shfl_u64(r, 0);
        const int m = (NPTS - 1) - (int)(r & 0xFFFFFFFFu);
        if (l == k) my_m = m;
        if ((m & 63) == l) {
            s_val[m] = 0u;
            unsigned long long nb = 0ull;
            for (int j = 0; j < NPTS / 64; ++j) {
                const int mm = j * 64 + l;
                const unsigned long long key =
                    ((unsigned long long)s_val[mm] << 32) | (uint32_t)(NPTS - 1 - mm);
                nb = key > nb ? key : nb;
            }
            bk = nb;
        }
    }

    if (l < KNN) {
        const int m = my_m;
        const float m0 = xb[m], m1 = xb[NPTS + m], m2 = xb[2 * NPTS + m];
        const float d0 = m0 - xn0, d1 = m1 - xn1, d2 = m2 - xn2;
        const float dist = sqrtf(((d0 * d0 + d1 * d1) + d2 * d2) + 1e-12f);
        const size_t base = ((size_t)b * NPTS + n) * KNN + l;
        idx_out[base]  = m;
        dist_out[base] = dist;
    }
}

// ---------------------------------------------------------------------------
// Weight prep: fragment-ordered bf16 B-operands for mfma_f32_16x16x32_bf16.
// frag[((nt*KT+kt)*64 + lane)*8 + j] = bf16(w[n*C + c]), n = nt*16+(lane&15),
// c = kt*32 + (lane>>4)*8 + j, zero-padded for c >= C.
__global__ void prep_wfrag(const float* __restrict__ w, uint16_t* __restrict__ frag,
                           int C, int NT, int KT) {
    const int i = blockIdx.x * 256 + threadIdx.x;   // one (nt,kt,lane)
    if (i >= NT * KT * 64) return;
    const int lane = i & 63;
    const int kt   = (i >> 6) % KT;
    const int nt   = (i >> 6) / KT;
    const int n    = nt * 16 + (lane & 15);
    const int c0   = kt * 32 + (lane >> 4) * 8;
    uint16_t o[8];
    #pragma unroll
    for (int j = 0; j < 8; ++j) {
        const int c = c0 + j;
        o[j] = (c < C) ? f2bf(w[(size_t)n * C + c]) : (uint16_t)0;
    }
    uint16_t* dst = frag + (size_t)i * 8;
    #pragma unroll
    for (int j = 0; j < 8; ++j) dst[j] = o[j];
}

// ---------------------------------------------------------------------------
// One MFMA conv layer: in (LDS bf16, [80][IN_STRIDE]) x wf -> out (LDS bf16,
// [80][OUT_STRIDE], relu'd). NT_TOT n-tiles split over 4 waves.
template <int NT_TOT, int KT, int IN_STRIDE, int OUT_STRIDE>
__device__ __forceinline__ void mfma_layer(const uint16_t* __restrict__ in,
                                           uint16_t* __restrict__ out,
                                           const uint16_t* __restrict__ wf,
                                           int wave, int lane) {
    constexpr int NT_W = NT_TOT / 4;
    const int col = lane & 15, quad = lane >> 4;
    #pragma unroll
    for (int ni = 0; ni < NT_W; ++ni) {
        const int nt = wave * NT_W + ni;
        short8 bfrag[KT];
        #pragma unroll
        for (int k = 0; k < KT; ++k)
            bfrag[k] = *(const short8*)(wf + ((size_t)(nt * KT + k) * 64 + lane) * 8);
        #pragma unroll
        for (int mt = 0; mt < 5; ++mt) {
            floatx4 acc = {0.f, 0.f, 0.f, 0.f};
            #pragma unroll
            for (int k = 0; k < KT; ++k) {
                const short8 af = *(const short8*)(in + (mt * 16 + col) * IN_STRIDE
                                                      + k * 32 + quad * 8);
                acc = __builtin_amdgcn_mfma_f32_16x16x32_bf16(af, bfrag[k], acc, 0, 0, 0);
            }
            #pragma unroll
            for (int r = 0; r < 4; ++r) {
                const float v = acc[r] > 0.f ? acc[r] : 0.f;
                out[(mt * 16 + quad * 4 + r) * OUT_STRIDE + nt * 16 + col] = f2bf(v);
            }
        }
    }
}

// max over the 20 k-rows of each point, bf16 (non-negative -> integer max ok)
template <int O, int STRIDE>
__device__ __forceinline__ void maxk(const uint16_t* __restrict__ h,
                                     float* __restrict__ cat_ws, int catoff,
                                     int t, int b, int n0) {
    constexpr int G = O / 8;
    if (t < P * G) {
        const int p = t / G, g = t % G;
        uint16_t mx[8];
        #pragma unroll
        for (int j = 0; j < 8; ++j) mx[j] = 0;
        for (int k = 0; k < KNN; ++k) {
            const uint16_t* row = h + (p * KNN + k) * STRIDE + g * 8;
            #pragma unroll
            for (int j = 0; j < 8; ++j) mx[j] = row[j] > mx[j] ? row[j] : mx[j];
        }
        float* dst = cat_ws + ((size_t)b * NPTS + n0 + p) * 512 + catoff + g * 8;
        #pragma unroll
        for (int j = 0; j < 8; ++j) dst[j] = bf2f(mx[j]);
    }
}

// ---------------------------------------------------------------------------
// Fused MLP, MFMA edition. Block = 4 points, 256 threads (4 waves).
// LDS strides: feat 40, h1/h2 72, h3 136 (all +8 pad -> 4-bank row shift,
// only free 2-way conflicts on ds_read_b128).
__global__ __launch_bounds__(256) void fused_mlp_mfma(
    const float* __restrict__ x,
    const int*   __restrict__ idx_ws,
    const float* __restrict__ dist_ws,
    const uint16_t* __restrict__ wf1,
    const uint16_t* __restrict__ wf2,
    const uint16_t* __restrict__ wf3,
    const uint16_t* __restrict__ wf4,
    float* __restrict__ cat_ws)
{
    const int n0 = blockIdx.x * P, b = blockIdx.y, t = threadIdx.x;
    const int wave = t >> 6, lane = t & 63;

    __shared__ __align__(16) uint16_t bufA[12800];  // feat(3200) / h2(5760) / slabs(12800)
    __shared__ __align__(16) uint16_t bufB[10880];  // h1(5760) / h3(10880)

    // ---- stage feat: [80][40] bf16, cols 0-2 xc, 3-5 nbr, 6-25 dist, 26+ zero
    for (int i = t; i < 1600; i += 256) ((uint32_t*)bufA)[i] = 0;
    __syncthreads();
    {
        const float* xb = x + (size_t)b * 3 * NPTS;
        if (t < P * KNN) {
            const int p = t / KNN, k = t % KNN;
            const int n = n0 + p;
            const size_t base = ((size_t)b * NPTS + n) * KNN + k;
            const int   m = idx_ws[base];
            const float d = dist_ws[base];
            uint16_t* fr = bufA + t * 40;
            fr[0] = f2bf(xb[n]);        fr[1] = f2bf(xb[NPTS + n]);
            fr[2] = f2bf(xb[2 * NPTS + n]);
            fr[3] = f2bf(xb[m]);        fr[4] = f2bf(xb[NPTS + m]);
            fr[5] = f2bf(xb[2 * NPTS + m]);
            const uint16_t db = f2bf(d);
            #pragma unroll
            for (int j = 0; j < KNN; ++j) bufA[(p * KNN + j) * 40 + 6 + k] = db;
        }
    }
    __syncthreads();

    // ---- L1: feat(A) -> h1(B)
    mfma_layer<4, 1, 40, 72>(bufA, bufB, wf1, wave, lane);
    __syncthreads();

    // ---- L2: h1(B) -> h2(A); x1 = maxk(h1)
    maxk<64, 72>(bufB, cat_ws, 0, t, b, n0);
    mfma_layer<4, 2, 72, 72>(bufB, bufA, wf2, wave, lane);
    __syncthreads();

    // ---- L3: h2(A) -> h3(B); x2 = maxk(h2)
    maxk<64, 72>(bufA, cat_ws, 64, t, b, n0);
    mfma_layer<8, 2, 72, 136>(bufA, bufB, wf3, wave, lane);
    __syncthreads();

    // ---- L4: h3(B) -> per-wave slab (A) -> relu+max -> cat; x3 = maxk(h3)
    maxk<128, 136>(bufB, cat_ws, 128, t, b, n0);
    {
        float* slab = (float*)bufA + wave * 1600;   // [80][20] f32, wave-private
        const int col = lane & 15, quad = lane >> 4;
        #pragma unroll
        for (int ni = 0; ni < 4; ++ni) {
            const int nt = wave * 4 + ni;
            short8 bfrag[4];
            #pragma unroll
            for (int k = 0; k < 4; ++k)
                bfrag[k] = *(const short8*)(wf4 + ((size_t)(nt * 4 + k) * 64 + lane) * 8);
            #pragma unroll
            for (int mt = 0; mt < 5; ++mt) {
                floatx4 acc = {0.f, 0.f, 0.f, 0.f};
                #pragma unroll
                for (int k = 0; k < 4; ++k) {
                    const short8 af = *(const short8*)(bufB + (mt * 16 + col) * 136
                                                           + k * 32 + quad * 8);
                    acc = __builtin_amdgcn_mfma_f32_16x16x32_bf16(af, bfrag[k], acc, 0, 0, 0);
                }
                #pragma unroll
                for (int r = 0; r < 4; ++r)
                    slab[(mt * 16 + quad * 4 + r) * 20 + col] = fmaxf(acc[r], 0.f);
            }
            // wave-private slab: in-order LDS per wave, no barrier needed.
            const int p = lane >> 4, grp = (lane >> 2) & 3, kq = lane & 3;
            floatx4 mx = {0.f, 0.f, 0.f, 0.f};
            #pragma unroll
            for (int i = 0; i < 5; ++i) {
                const floatx4 v = *(const floatx4*)&slab[(p * KNN + kq * 5 + i) * 20 + grp * 4];
                mx[0] = fmaxf(mx[0], v[0]); mx[1] = fmaxf(mx[1], v[1]);
                mx[2] = fmaxf(mx[2], v[2]); mx[3] = fmaxf(mx[3], v[3]);
            }
            #pragma unroll
            for (int r = 0; r < 4; ++r) {
                mx[r] = fmaxf(mx[r], __shfl_xor(mx[r], 1));
                mx[r] = fmaxf(mx[r], __shfl_xor(mx[r], 2));
            }
            if (kq == 0) {
                float* dst = cat_ws + ((size_t)b * NPTS + n0 + p) * 512
                           + 256 + nt * 16 + grp * 4;
                *(floatx4*)dst = mx;
            }
        }
    }
}

// ---------------------------------------------------------------------------
// Final GEMM (unchanged fp32): out[b,o,n] = relu( sum_c w5[o,c] * cat[b,n,c] )
__global__ __launch_bounds__(256) void final_gemm(
    const float* __restrict__ w5,   // (512,512)
    const float* __restrict__ cat,  // (B*N, 512)
    float* __restrict__ out)        // (B,512,N)
{
    const int b  = blockIdx.z;
    const int o0 = blockIdx.y * 64;
    const int n0 = blockIdx.x * 64;
    const int t  = threadIdx.x;
    const int tx = t & 15, ty = t >> 4;
    __shared__ float As[16][68];
    __shared__ float Bs[16][68];
    float acc[4][4] = {{0.f, 0.f, 0.f, 0.f}, {0.f, 0.f, 0.f, 0.f},
                       {0.f, 0.f, 0.f, 0.f}, {0.f, 0.f, 0.f, 0.f}};
    const int lr = t >> 2;
    const int lc = (t & 3) * 4;
    const float* arow = w5 + (size_t)(o0 + lr) * 512;
    const float* brow = cat + ((size_t)b * NPTS + n0 + lr) * 512;

    for (int ck = 0; ck < 512; ck += 16) {
        const float4 av = *(const float4*)(arow + ck + lc);
        const float4 bv = *(const float4*)(brow + ck + lc);
        As[lc + 0][lr] = av.x; As[lc + 1][lr] = av.y;
        As[lc + 2][lr] = av.z; As[lc + 3][lr] = av.w;
        Bs[lc + 0][lr] = bv.x; Bs[lc + 1][lr] = bv.y;
        Bs[lc + 2][lr] = bv.z; Bs[lc + 3][lr] = bv.w;
        __syncthreads();
        #pragma unroll
        for (int c = 0; c < 16; ++c) {
            const float4 a  = *(const float4*)&As[c][ty * 4];
            const float4 bb = *(const float4*)&Bs[c][tx * 4];
            acc[0][0] = fmaf(a.x, bb.x, acc[0][0]);
            acc[0][1] = fmaf(a.x, bb.y, acc[0][1]);
            acc[0][2] = fmaf(a.x, bb.z, acc[0][2]);
            acc[0][3] = fmaf(a.x, bb.w, acc[0][3]);
            acc[1][0] = fmaf(a.y, bb.x, acc[1][0]);
            acc[1][1] = fmaf(a.y, bb.y, acc[1][1]);
            acc[1][2] = fmaf(a.y, bb.z, acc[1][2]);
            acc[1][3] = fmaf(a.y, bb.w, acc[1][3]);
            acc[2][0] = fmaf(a.z, bb.x, acc[2][0]);
            acc[2][1] = fmaf(a.z, bb.y, acc[2][1]);
            acc[2][2] = fmaf(a.z, bb.z, acc[2][2]);
            acc[2][3] = fmaf(a.z, bb.w, acc[2][3]);
            acc[3][0] = fmaf(a.w, bb.x, acc[3][0]);
            acc[3][1] = fmaf(a.w, bb.y, acc[3][1]);
            acc[3][2] = fmaf(a.w, bb.z, acc[3][2]);
            acc[3][3] = fmaf(a.w, bb.w, acc[3][3]);
        }
        __syncthreads();
    }
    #pragma unroll
    for (int i = 0; i < 4; ++i) {
        float4 v;
        v.x = fmaxf(acc[i][0], 0.f);
        v.y = fmaxf(acc[i][1], 0.f);
        v.z = fmaxf(acc[i][2], 0.f);
        v.w = fmaxf(acc[i][3], 0.f);
        *(float4*)&out[((size_t)b * 512 + o0 + ty * 4 + i) * NPTS + n0 + tx * 4] = v;
    }
}

// ---------------------------------------------------------------------------
extern "C" void kernel_launch(void* const* d_in, const int* in_sizes, int n_in,
                              void* d_out, int out_size, void* d_ws, size_t ws_size,
                              hipStream_t stream) {
    const float* x  = (const float*)d_in[0];  // (8,3,4096)
    const float* w1 = (const float*)d_in[1];  // (64,26)
    const float* w2 = (const float*)d_in[2];  // (64,64)
    const float* w3 = (const float*)d_in[3];  // (128,64)
    const float* w4 = (const float*)d_in[4];  // (256,128)
    const float* w5 = (const float*)d_in[5];  // (512,512)
    float* out = (float*)d_out;               // (8,512,4096) fp32

    // workspace layout (bytes):
    //   [0)         idx_ws   B*N*K int    = 2,621,440
    //   [2621440)   dist_ws  B*N*K f32    = 2,621,440
    //   [5242880)   cat_ws   B*N*512 f32  = 67,108,864
    //   [72351744)  wf1 bf16 frag 4 KB; wf2 8 KB; wf3 16 KB; wf4 64 KB
    char* ws = (char*)d_ws;
    int*      idx_ws  = (int*)ws;
    float*    dist_ws = (float*)(ws + 2621440);
    float*    cat_ws  = (float*)(ws + 5242880);
    uint16_t* wf1     = (uint16_t*)(ws + 72351744);
    uint16_t* wf2     = (uint16_t*)(ws + 72351744 + 4096);
    uint16_t* wf3     = (uint16_t*)(ws + 72351744 + 4096 + 8192);
    uint16_t* wf4     = (uint16_t*)(ws + 72351744 + 4096 + 8192 + 16384);

    prep_wfrag<<<dim3(1), 256, 0, stream>>>(w1, wf1, 26,  4, 1);   // 256 frags... threads
    prep_wfrag<<<dim3(2), 256, 0, stream>>>(w2, wf2, 64,  4, 2);
    prep_wfrag<<<dim3(4), 256, 0, stream>>>(w3, wf3, 64,  8, 2);
    prep_wfrag<<<dim3(16), 256, 0, stream>>>(w4, wf4, 128, 16, 4);

    topk_kernel<<<dim3(NPTS, NB), 64, 0, stream>>>(x, idx_ws, dist_ws);
    fused_mlp_mfma<<<dim3(NPTS / P, NB), 256, 0, stream>>>(
        x, idx_ws, dist_ws, wf1, wf2, wf3, wf4, cat_ws);
    final_gemm<<<dim3(NPTS / 64, 512 / 64, NB), 256, 0, stream>>>(w5, cat_ws, out);
}

// Round 3
// 581.416 us; speedup vs baseline: 3.4400x; 1.5960x over previous
//
#include <hip/hip_runtime.h>
#include <cstdint>
#include <cstddef>

#define NB   8
#define NPTS 4096
#define KNN  20
#define P    4   // points per fused-MLP block (M = P*KNN = 80 rows = 5 m-tiles)

typedef __attribute__((ext_vector_type(8))) short  short8;
typedef __attribute__((ext_vector_type(4))) float  floatx4;

__device__ __forceinline__ uint16_t f2bf(float f) {
    uint32_t u = __float_as_uint(f);
    uint32_t r = (u + 0x7FFFu + ((u >> 16) & 1u)) >> 16;   // RNE
    return (uint16_t)r;
}
__device__ __forceinline__ float bf2f(uint16_t h) {
    return __uint_as_float(((uint32_t)h) << 16);
}

// ordered-float transform: monotone fp32 -> uint32 (no NaNs present)
__device__ __forceinline__ uint32_t f2ord(float v) {
    uint32_t u = __float_as_uint(v);
    uint32_t m = (uint32_t)((int32_t)u >> 31) | 0x80000000u;
    return u ^ m;
}

__device__ __forceinline__ unsigned long long shfl_xor_u64(unsigned long long v, int m) {
    uint32_t lo = (uint32_t)__shfl_xor((int)(uint32_t)v, m, 64);
    uint32_t hi = (uint32_t)__shfl_xor((int)(uint32_t)(v >> 32), m, 64);
    return ((unsigned long long)hi << 32) | lo;
}

// compare-swap keeping larger in a
__device__ __forceinline__ void cs_u64(unsigned long long& a, unsigned long long& b) {
    unsigned long long hi = a > b ? a : b;
    unsigned long long lo = a > b ? b : a;
    a = hi; b = lo;
}

// ---------------------------------------------------------------------------
// Prep: pack (x,y,z,||x||^2) per point; sq uses the SAME fma order as the
// pair formula everywhere -> bitwise-identical pair values to prior rounds.
__global__ __launch_bounds__(256) void prep_xyzs(
    const float* __restrict__ x,      // (B,3,N)
    float4* __restrict__ xyzs)        // (B,N)
{
    const int i = blockIdx.x * 256 + threadIdx.x;
    if (i >= NB * NPTS) return;
    const int b = i / NPTS, n = i - b * NPTS;
    const float* xb = x + (size_t)b * 3 * NPTS;
    const float x0 = xb[n], x1 = xb[NPTS + n], x2 = xb[2 * NPTS + n];
    float4 v;
    v.x = x0; v.y = x1; v.z = x2;
    v.w = fmaf(x2, x2, fmaf(x1, x1, x0 * x0));
    xyzs[i] = v;
}

// ---------------------------------------------------------------------------
// Top-20 selection: one wave per point, lane l owns columns m%64==l.
// Lane-local register top-3 (sorted desc u64 keys) + 64-bit consumed mask;
// refill by recompute only if a lane is popped >3 times (P ~ 3e-4).
__global__ __launch_bounds__(256) void topk_kernel(
    const float4* __restrict__ xyzs,  // (B,N) packed
    int*   __restrict__ idx_out,      // (B,N,K)
    float* __restrict__ dist_out)     // (B,N,K)
{
    const int t = threadIdx.x;
    const int wave = t >> 6, l = t & 63;
    const int n = blockIdx.x * 4 + wave;
    const int b = blockIdx.y;
    const float4* xq = xyzs + (size_t)b * NPTS;

    const float4 pn = xq[n];
    const float xn0 = pn.x, xn1 = pn.y, xn2 = pn.z, sqn = pn.w;

    unsigned long long L0 = 0ull, L1 = 0ull, L2 = 0ull;
    unsigned long long consumed = 0ull;

    for (int j = 0; j < 64; ++j) {
        const int m = j * 64 + l;
        const float4 pm = xq[m];
        const float dot = fmaf(xn2, pm.z, fmaf(xn1, pm.y, xn0 * pm.x));
        const float pair = 2.0f * dot - sqn - pm.w;
        const unsigned long long key =
            ((unsigned long long)f2ord(pair) << 32) | (uint32_t)(NPTS - 1 - m);
        if (key > L2) { L2 = key; cs_u64(L1, L2); cs_u64(L0, L1); }
    }

    int my_m = 0;
    for (int k = 0; k < KNN; ++k) {
        if (L0 == 0ull) {  // rare refill: rebuild top-3 of unconsumed columns
            L1 = 0ull; L2 = 0ull;
            for (int j = 0; j < 64; ++j) {
                if ((consumed >> j) & 1ull) continue;
                const int m = j * 64 + l;
                const float4 pm = xq[m];
                const float dot = fmaf(xn2, pm.z, fmaf(xn1, pm.y, xn0 * pm.x));
                const float pair = 2.0f * dot - sqn - pm.w;
                const unsigned long long key =
                    ((unsigned long long)f2ord(pair) << 32) | (uint32_t)(NPTS - 1 - m);
                if (key > L2) { L2 = key; cs_u64(L1, L2); cs_u64(L0, L1); }
            }
        }
        unsigned long long w = L0;
        #pragma unroll
        for (int mask = 1; mask < 64; mask <<= 1) {
            const unsigned long long o = shfl_xor_u64(w, mask);
            w = o > w ? o : w;
        }
        const int m = (NPTS - 1) - (int)(w & 0xFFFFFFFFull);
        if (l == k) my_m = m;
        if ((m & 63) == l) {           // owner pops its head
            L0 = L1; L1 = L2; L2 = 0ull;
            consumed |= 1ull << (m >> 6);
        }
    }

    if (l < KNN) {
        const float4 pm = xq[my_m];
        const float d0 = pm.x - xn0, d1 = pm.y - xn1, d2 = pm.z - xn2;
        const float dist = sqrtf(((d0 * d0 + d1 * d1) + d2 * d2) + 1e-12f);
        const size_t base = ((size_t)b * NPTS + n) * KNN + l;
        idx_out[base]  = my_m;
        dist_out[base] = dist;
    }
}

// ---------------------------------------------------------------------------
// Weight prep: fragment-ordered bf16 B-operands for mfma_f32_16x16x32_bf16.
__global__ void prep_wfrag(const float* __restrict__ w, uint16_t* __restrict__ frag,
                           int C, int NT, int KT) {
    const int i = blockIdx.x * 256 + threadIdx.x;   // one (nt,kt,lane)
    if (i >= NT * KT * 64) return;
    const int lane = i & 63;
    const int kt   = (i >> 6) % KT;
    const int nt   = (i >> 6) / KT;
    const int n    = nt * 16 + (lane & 15);
    const int c0   = kt * 32 + (lane >> 4) * 8;
    uint16_t o[8];
    #pragma unroll
    for (int j = 0; j < 8; ++j) {
        const int c = c0 + j;
        o[j] = (c < C) ? f2bf(w[(size_t)n * C + c]) : (uint16_t)0;
    }
    uint16_t* dst = frag + (size_t)i * 8;
    #pragma unroll
    for (int j = 0; j < 8; ++j) dst[j] = o[j];
}

// ---------------------------------------------------------------------------
// One MFMA conv layer: in (LDS bf16, [80][IN_STRIDE]) x wf -> out (LDS bf16,
// [80][OUT_STRIDE], relu'd). NT_TOT n-tiles split over 4 waves.
template <int NT_TOT, int KT, int IN_STRIDE, int OUT_STRIDE>
__device__ __forceinline__ void mfma_layer(const uint16_t* __restrict__ in,
                                           uint16_t* __restrict__ out,
                                           const uint16_t* __restrict__ wf,
                                           int wave, int lane) {
    constexpr int NT_W = NT_TOT / 4;
    const int col = lane & 15, quad = lane >> 4;
    #pragma unroll
    for (int ni = 0; ni < NT_W; ++ni) {
        const int nt = wave * NT_W + ni;
        short8 bfrag[KT];
        #pragma unroll
        for (int k = 0; k < KT; ++k)
            bfrag[k] = *(const short8*)(wf + ((size_t)(nt * KT + k) * 64 + lane) * 8);
        #pragma unroll
        for (int mt = 0; mt < 5; ++mt) {
            floatx4 acc = {0.f, 0.f, 0.f, 0.f};
            #pragma unroll
            for (int k = 0; k < KT; ++k) {
                const short8 af = *(const short8*)(in + (mt * 16 + col) * IN_STRIDE
                                                      + k * 32 + quad * 8);
                acc = __builtin_amdgcn_mfma_f32_16x16x32_bf16(af, bfrag[k], acc, 0, 0, 0);
            }
            #pragma unroll
            for (int r = 0; r < 4; ++r) {
                const float v = acc[r] > 0.f ? acc[r] : 0.f;
                out[(mt * 16 + quad * 4 + r) * OUT_STRIDE + nt * 16 + col] = f2bf(v);
            }
        }
    }
}

// max over the 20 k-rows of each point, bf16 (non-negative -> integer max ok)
template <int O, int STRIDE>
__device__ __forceinline__ void maxk(const uint16_t* __restrict__ h,
                                     float* __restrict__ cat_ws, int catoff,
                                     int t, int b, int n0) {
    constexpr int G = O / 8;
    if (t < P * G) {
        const int p = t / G, g = t % G;
        uint16_t mx[8];
        #pragma unroll
        for (int j = 0; j < 8; ++j) mx[j] = 0;
        for (int k = 0; k < KNN; ++k) {
            const uint16_t* row = h + (p * KNN + k) * STRIDE + g * 8;
            #pragma unroll
            for (int j = 0; j < 8; ++j) mx[j] = row[j] > mx[j] ? row[j] : mx[j];
        }
        float* dst = cat_ws + ((size_t)b * NPTS + n0 + p) * 512 + catoff + g * 8;
        #pragma unroll
        for (int j = 0; j < 8; ++j) dst[j] = bf2f(mx[j]);
    }
}

// ---------------------------------------------------------------------------
// Fused MLP, MFMA edition. Block = 4 points, 256 threads (4 waves).
__global__ __launch_bounds__(256) void fused_mlp_mfma(
    const float* __restrict__ x,
    const int*   __restrict__ idx_ws,
    const float* __restrict__ dist_ws,
    const uint16_t* __restrict__ wf1,
    const uint16_t* __restrict__ wf2,
    const uint16_t* __restrict__ wf3,
    const uint16_t* __restrict__ wf4,
    float* __restrict__ cat_ws)
{
    const int n0 = blockIdx.x * P, b = blockIdx.y, t = threadIdx.x;
    const int wave = t >> 6, lane = t & 63;

    __shared__ __align__(16) uint16_t bufA[12800];  // feat(3200) / h2(5760) / slabs(12800)
    __shared__ __align__(16) uint16_t bufB[10880];  // h1(5760) / h3(10880)

    // ---- stage feat: [80][40] bf16, cols 0-2 xc, 3-5 nbr, 6-25 dist, 26+ zero
    for (int i = t; i < 1600; i += 256) ((uint32_t*)bufA)[i] = 0;
    __syncthreads();
    {
        const float* xb = x + (size_t)b * 3 * NPTS;
        if (t < P * KNN) {
            const int p = t / KNN, k = t % KNN;
            const int n = n0 + p;
            const size_t base = ((size_t)b * NPTS + n) * KNN + k;
            const int   m = idx_ws[base];
            const float d = dist_ws[base];
            uint16_t* fr = bufA + t * 40;
            fr[0] = f2bf(xb[n]);        fr[1] = f2bf(xb[NPTS + n]);
            fr[2] = f2bf(xb[2 * NPTS + n]);
            fr[3] = f2bf(xb[m]);        fr[4] = f2bf(xb[NPTS + m]);
            fr[5] = f2bf(xb[2 * NPTS + m]);
            const uint16_t db = f2bf(d);
            #pragma unroll
            for (int j = 0; j < KNN; ++j) bufA[(p * KNN + j) * 40 + 6 + k] = db;
        }
    }
    __syncthreads();

    // ---- L1: feat(A) -> h1(B)
    mfma_layer<4, 1, 40, 72>(bufA, bufB, wf1, wave, lane);
    __syncthreads();

    // ---- L2: h1(B) -> h2(A); x1 = maxk(h1)
    maxk<64, 72>(bufB, cat_ws, 0, t, b, n0);
    mfma_layer<4, 2, 72, 72>(bufB, bufA, wf2, wave, lane);
    __syncthreads();

    // ---- L3: h2(A) -> h3(B); x2 = maxk(h2)
    maxk<64, 72>(bufA, cat_ws, 64, t, b, n0);
    mfma_layer<8, 2, 72, 136>(bufA, bufB, wf3, wave, lane);
    __syncthreads();

    // ---- L4: h3(B) -> per-wave slab (A) -> relu+max -> cat; x3 = maxk(h3)
    maxk<128, 136>(bufB, cat_ws, 128, t, b, n0);
    {
        float* slab = (float*)bufA + wave * 1600;   // [80][20] f32, wave-private
        const int col = lane & 15, quad = lane >> 4;
        #pragma unroll
        for (int ni = 0; ni < 4; ++ni) {
            const int nt = wave * 4 + ni;
            short8 bfrag[4];
            #pragma unroll
            for (int k = 0; k < 4; ++k)
                bfrag[k] = *(const short8*)(wf4 + ((size_t)(nt * 4 + k) * 64 + lane) * 8);
            #pragma unroll
            for (int mt = 0; mt < 5; ++mt) {
                floatx4 acc = {0.f, 0.f, 0.f, 0.f};
                #pragma unroll
                for (int k = 0; k < 4; ++k) {
                    const short8 af = *(const short8*)(bufB + (mt * 16 + col) * 136
                                                           + k * 32 + quad * 8);
                    acc = __builtin_amdgcn_mfma_f32_16x16x32_bf16(af, bfrag[k], acc, 0, 0, 0);
                }
                #pragma unroll
                for (int r = 0; r < 4; ++r)
                    slab[(mt * 16 + quad * 4 + r) * 20 + col] = fmaxf(acc[r], 0.f);
            }
            const int p = lane >> 4, grp = (lane >> 2) & 3, kq = lane & 3;
            floatx4 mx = {0.f, 0.f, 0.f, 0.f};
            #pragma unroll
            for (int i = 0; i < 5; ++i) {
                const floatx4 v = *(const floatx4*)&slab[(p * KNN + kq * 5 + i) * 20 + grp * 4];
                mx[0] = fmaxf(mx[0], v[0]); mx[1] = fmaxf(mx[1], v[1]);
                mx[2] = fmaxf(mx[2], v[2]); mx[3] = fmaxf(mx[3], v[3]);
            }
            #pragma unroll
            for (int r = 0; r < 4; ++r) {
                mx[r] = fmaxf(mx[r], __shfl_xor(mx[r], 1));
                mx[r] = fmaxf(mx[r], __shfl_xor(mx[r], 2));
            }
            if (kq == 0) {
                float* dst = cat_ws + ((size_t)b * NPTS + n0 + p) * 512
                           + 256 + nt * 16 + grp * 4;
                *(floatx4*)dst = mx;
            }
        }
    }
}

// ---------------------------------------------------------------------------
// Final GEMM (fp32): out[b,o,n] = relu( sum_c w5[o,c] * cat[b,n,c] )
__global__ __launch_bounds__(256) void final_gemm(
    const float* __restrict__ w5,   // (512,512)
    const float* __restrict__ cat,  // (B*N, 512)
    float* __restrict__ out)        // (B,512,N)
{
    const int b  = blockIdx.z;
    const int o0 = blockIdx.y * 64;
    const int n0 = blockIdx.x * 64;
    const int t  = threadIdx.x;
    const int tx = t & 15, ty = t >> 4;
    __shared__ float As[16][68];
    __shared__ float Bs[16][68];
    float acc[4][4] = {{0.f, 0.f, 0.f, 0.f}, {0.f, 0.f, 0.f, 0.f},
                       {0.f, 0.f, 0.f, 0.f}, {0.f, 0.f, 0.f, 0.f}};
    const int lr = t >> 2;
    const int lc = (t & 3) * 4;
    const float* arow = w5 + (size_t)(o0 + lr) * 512;
    const float* brow = cat + ((size_t)b * NPTS + n0 + lr) * 512;

    for (int ck = 0; ck < 512; ck += 16) {
        const float4 av = *(const float4*)(arow + ck + lc);
        const float4 bv = *(const float4*)(brow + ck + lc);
        As[lc + 0][lr] = av.x; As[lc + 1][lr] = av.y;
        As[lc + 2][lr] = av.z; As[lc + 3][lr] = av.w;
        Bs[lc + 0][lr] = bv.x; Bs[lc + 1][lr] = bv.y;
        Bs[lc + 2][lr] = bv.z; Bs[lc + 3][lr] = bv.w;
        __syncthreads();
        #pragma unroll
        for (int c = 0; c < 16; ++c) {
            const float4 a  = *(const float4*)&As[c][ty * 4];
            const float4 bb = *(const float4*)&Bs[c][tx * 4];
            acc[0][0] = fmaf(a.x, bb.x, acc[0][0]);
            acc[0][1] = fmaf(a.x, bb.y, acc[0][1]);
            acc[0][2] = fmaf(a.x, bb.z, acc[0][2]);
            acc[0][3] = fmaf(a.x, bb.w, acc[0][3]);
            acc[1][0] = fmaf(a.y, bb.x, acc[1][0]);
            acc[1][1] = fmaf(a.y, bb.y, acc[1][1]);
            acc[1][2] = fmaf(a.y, bb.z, acc[1][2]);
            acc[1][3] = fmaf(a.y, bb.w, acc[1][3]);
            acc[2][0] = fmaf(a.z, bb.x, acc[2][0]);
            acc[2][1] = fmaf(a.z, bb.y, acc[2][1]);
            acc[2][2] = fmaf(a.z, bb.z, acc[2][2]);
            acc[2][3] = fmaf(a.z, bb.w, acc[2][3]);
            acc[3][0] = fmaf(a.w, bb.x, acc[3][0]);
            acc[3][1] = fmaf(a.w, bb.y, acc[3][1]);
            acc[3][2] = fmaf(a.w, bb.z, acc[3][2]);
            acc[3][3] = fmaf(a.w, bb.w, acc[3][3]);
        }
        __syncthreads();
    }
    #pragma unroll
    for (int i = 0; i < 4; ++i) {
        float4 v;
        v.x = fmaxf(acc[i][0], 0.f);
        v.y = fmaxf(acc[i][1], 0.f);
        v.z = fmaxf(acc[i][2], 0.f);
        v.w = fmaxf(acc[i][3], 0.f);
        *(float4*)&out[((size_t)b * 512 + o0 + ty * 4 + i) * NPTS + n0 + tx * 4] = v;
    }
}

// ---------------------------------------------------------------------------
extern "C" void kernel_launch(void* const* d_in, const int* in_sizes, int n_in,
                              void* d_out, int out_size, void* d_ws, size_t ws_size,
                              hipStream_t stream) {
    const float* x  = (const float*)d_in[0];  // (8,3,4096)
    const float* w1 = (const float*)d_in[1];  // (64,26)
    const float* w2 = (const float*)d_in[2];  // (64,64)
    const float* w3 = (const float*)d_in[3];  // (128,64)
    const float* w4 = (const float*)d_in[4];  // (256,128)
    const float* w5 = (const float*)d_in[5];  // (512,512)
    float* out = (float*)d_out;               // (8,512,4096) fp32

    // workspace layout (bytes):
    //   [0)         idx_ws   B*N*K int    = 2,621,440
    //   [2621440)   dist_ws  B*N*K f32    = 2,621,440
    //   [5242880)   cat_ws   B*N*512 f32  = 67,108,864
    //               (xyzs aliases cat_ws[0:512KB]: consumed by topk BEFORE
    //                fused_mlp writes cat — stream-ordered, safe)
    //   [72351744)  wf1 bf16 frag 4 KB; wf2 8 KB; wf3 16 KB; wf4 64 KB
    char* ws = (char*)d_ws;
    int*      idx_ws  = (int*)ws;
    float*    dist_ws = (float*)(ws + 2621440);
    float*    cat_ws  = (float*)(ws + 5242880);
    float4*   xyzs    = (float4*)(ws + 5242880);   // alias, 512 KB
    uint16_t* wf1     = (uint16_t*)(ws + 72351744);
    uint16_t* wf2     = (uint16_t*)(ws + 72351744 + 4096);
    uint16_t* wf3     = (uint16_t*)(ws + 72351744 + 4096 + 8192);
    uint16_t* wf4     = (uint16_t*)(ws + 72351744 + 4096 + 8192 + 16384);

    prep_wfrag<<<dim3(1), 256, 0, stream>>>(w1, wf1, 26,  4, 1);
    prep_wfrag<<<dim3(2), 256, 0, stream>>>(w2, wf2, 64,  4, 2);
    prep_wfrag<<<dim3(4), 256, 0, stream>>>(w3, wf3, 64,  8, 2);
    prep_wfrag<<<dim3(16), 256, 0, stream>>>(w4, wf4, 128, 16, 4);
    prep_xyzs<<<dim3((NB * NPTS + 255) / 256), 256, 0, stream>>>(x, xyzs);

    topk_kernel<<<dim3(NPTS / 4, NB), 256, 0, stream>>>(xyzs, idx_ws, dist_ws);
    fused_mlp_mfma<<<dim3(NPTS / P, NB), 256, 0, stream>>>(
        x, idx_ws, dist_ws, wf1, wf2, wf3, wf4, cat_ws);
    final_gemm<<<dim3(NPTS / 64, 512 / 64, NB), 256, 0, stream>>>(w5, cat_ws, out);
}

// Round 4
// 411.833 us; speedup vs baseline: 4.8566x; 1.4118x over previous
//
#include <hip/hip_runtime.h>
#include <cstdint>
#include <cstddef>

#define NB   8
#define NPTS 4096
#define KNN  20
#define P    4   // points per fused-MLP block (M = P*KNN = 80 rows = 5 m-tiles)

typedef __attribute__((ext_vector_type(8))) short    short8;
typedef __attribute__((ext_vector_type(4))) float    floatx4;
typedef __attribute__((ext_vector_type(4))) unsigned short ushort4v;

__device__ __forceinline__ uint16_t f2bf(float f) {
    uint32_t u = __float_as_uint(f);
    uint32_t r = (u + 0x7FFFu + ((u >> 16) & 1u)) >> 16;   // RNE
    return (uint16_t)r;
}
__device__ __forceinline__ float bf2f(uint16_t h) {
    return __uint_as_float(((uint32_t)h) << 16);
}

// ordered-float transform: monotone fp32 -> uint32 (no NaNs present)
__device__ __forceinline__ uint32_t f2ord(float v) {
    uint32_t u = __float_as_uint(v);
    uint32_t m = (uint32_t)((int32_t)u >> 31) | 0x80000000u;
    return u ^ m;
}

__device__ __forceinline__ unsigned long long shfl_xor_u64(unsigned long long v, int m) {
    uint32_t lo = (uint32_t)__shfl_xor((int)(uint32_t)v, m, 64);
    uint32_t hi = (uint32_t)__shfl_xor((int)(uint32_t)(v >> 32), m, 64);
    return ((unsigned long long)hi << 32) | lo;
}

// compare-swap keeping larger in a
__device__ __forceinline__ void cs_u64(unsigned long long& a, unsigned long long& b) {
    unsigned long long hi = a > b ? a : b;
    unsigned long long lo = a > b ? b : a;
    a = hi; b = lo;
}

// ---------------------------------------------------------------------------
// Prep: pack (x,y,z,||x||^2) per point; sq uses the SAME fma order as the
// pair formula everywhere -> bitwise-identical pair values to prior rounds.
__global__ __launch_bounds__(256) void prep_xyzs(
    const float* __restrict__ x,      // (B,3,N)
    float4* __restrict__ xyzs)        // (B,N)
{
    const int i = blockIdx.x * 256 + threadIdx.x;
    if (i >= NB * NPTS) return;
    const int b = i / NPTS, n = i - b * NPTS;
    const float* xb = x + (size_t)b * 3 * NPTS;
    const float x0 = xb[n], x1 = xb[NPTS + n], x2 = xb[2 * NPTS + n];
    float4 v;
    v.x = x0; v.y = x1; v.z = x2;
    v.w = fmaf(x2, x2, fmaf(x1, x1, x0 * x0));
    xyzs[i] = v;
}

// ---------------------------------------------------------------------------
// Top-20 selection: one wave per point, lane l owns columns m%64==l.
// Lane-local register top-3 (sorted desc u64 keys) + 64-bit consumed mask;
// refill by recompute only if a lane is popped >3 times (P ~ 3e-4).
__global__ __launch_bounds__(256) void topk_kernel(
    const float4* __restrict__ xyzs,  // (B,N) packed
    int*   __restrict__ idx_out,      // (B,N,K)
    float* __restrict__ dist_out)     // (B,N,K)
{
    const int t = threadIdx.x;
    const int wave = t >> 6, l = t & 63;
    const int n = blockIdx.x * 4 + wave;
    const int b = blockIdx.y;
    const float4* xq = xyzs + (size_t)b * NPTS;

    const float4 pn = xq[n];
    const float xn0 = pn.x, xn1 = pn.y, xn2 = pn.z, sqn = pn.w;

    unsigned long long L0 = 0ull, L1 = 0ull, L2 = 0ull;
    unsigned long long consumed = 0ull;

    for (int j = 0; j < 64; ++j) {
        const int m = j * 64 + l;
        const float4 pm = xq[m];
        const float dot = fmaf(xn2, pm.z, fmaf(xn1, pm.y, xn0 * pm.x));
        const float pair = 2.0f * dot - sqn - pm.w;
        const unsigned long long key =
            ((unsigned long long)f2ord(pair) << 32) | (uint32_t)(NPTS - 1 - m);
        if (key > L2) { L2 = key; cs_u64(L1, L2); cs_u64(L0, L1); }
    }

    int my_m = 0;
    for (int k = 0; k < KNN; ++k) {
        if (L0 == 0ull) {  // rare refill: rebuild top-3 of unconsumed columns
            L1 = 0ull; L2 = 0ull;
            for (int j = 0; j < 64; ++j) {
                if ((consumed >> j) & 1ull) continue;
                const int m = j * 64 + l;
                const float4 pm = xq[m];
                const float dot = fmaf(xn2, pm.z, fmaf(xn1, pm.y, xn0 * pm.x));
                const float pair = 2.0f * dot - sqn - pm.w;
                const unsigned long long key =
                    ((unsigned long long)f2ord(pair) << 32) | (uint32_t)(NPTS - 1 - m);
                if (key > L2) { L2 = key; cs_u64(L1, L2); cs_u64(L0, L1); }
            }
        }
        unsigned long long w = L0;
        #pragma unroll
        for (int mask = 1; mask < 64; mask <<= 1) {
            const unsigned long long o = shfl_xor_u64(w, mask);
            w = o > w ? o : w;
        }
        const int m = (NPTS - 1) - (int)(w & 0xFFFFFFFFull);
        if (l == k) my_m = m;
        if ((m & 63) == l) {           // owner pops its head
            L0 = L1; L1 = L2; L2 = 0ull;
            consumed |= 1ull << (m >> 6);
        }
    }

    if (l < KNN) {
        const float4 pm = xq[my_m];
        const float d0 = pm.x - xn0, d1 = pm.y - xn1, d2 = pm.z - xn2;
        const float dist = sqrtf(((d0 * d0 + d1 * d1) + d2 * d2) + 1e-12f);
        const size_t base = ((size_t)b * NPTS + n) * KNN + l;
        idx_out[base]  = my_m;
        dist_out[base] = dist;
    }
}

// ---------------------------------------------------------------------------
// Weight prep: fragment-ordered bf16 B-operands for mfma_f32_16x16x32_bf16.
__global__ void prep_wfrag(const float* __restrict__ w, uint16_t* __restrict__ frag,
                           int C, int NT, int KT) {
    const int i = blockIdx.x * 256 + threadIdx.x;   // one (nt,kt,lane)
    if (i >= NT * KT * 64) return;
    const int lane = i & 63;
    const int kt   = (i >> 6) % KT;
    const int nt   = (i >> 6) / KT;
    const int n    = nt * 16 + (lane & 15);
    const int c0   = kt * 32 + (lane >> 4) * 8;
    uint16_t o[8];
    #pragma unroll
    for (int j = 0; j < 8; ++j) {
        const int c = c0 + j;
        o[j] = (c < C) ? f2bf(w[(size_t)n * C + c]) : (uint16_t)0;
    }
    uint16_t* dst = frag + (size_t)i * 8;
    #pragma unroll
    for (int j = 0; j < 8; ++j) dst[j] = o[j];
}

// w5 (512,512) fp32 -> bf16 row-major
__global__ __launch_bounds__(256) void prep_w5bf(const float* __restrict__ w5,
                                                 uint16_t* __restrict__ w5b) {
    const int i = blockIdx.x * 256 + threadIdx.x;
    if (i < 512 * 512) w5b[i] = f2bf(w5[i]);
}

// ---------------------------------------------------------------------------
// One MFMA conv layer: in (LDS bf16, [80][IN_STRIDE]) x wf -> out (LDS bf16,
// [80][OUT_STRIDE], relu'd). NT_TOT n-tiles split over 4 waves.
template <int NT_TOT, int KT, int IN_STRIDE, int OUT_STRIDE>
__device__ __forceinline__ void mfma_layer(const uint16_t* __restrict__ in,
                                           uint16_t* __restrict__ out,
                                           const uint16_t* __restrict__ wf,
                                           int wave, int lane) {
    constexpr int NT_W = NT_TOT / 4;
    const int col = lane & 15, quad = lane >> 4;
    #pragma unroll
    for (int ni = 0; ni < NT_W; ++ni) {
        const int nt = wave * NT_W + ni;
        short8 bfrag[KT];
        #pragma unroll
        for (int k = 0; k < KT; ++k)
            bfrag[k] = *(const short8*)(wf + ((size_t)(nt * KT + k) * 64 + lane) * 8);
        #pragma unroll
        for (int mt = 0; mt < 5; ++mt) {
            floatx4 acc = {0.f, 0.f, 0.f, 0.f};
            #pragma unroll
            for (int k = 0; k < KT; ++k) {
                const short8 af = *(const short8*)(in + (mt * 16 + col) * IN_STRIDE
                                                      + k * 32 + quad * 8);
                acc = __builtin_amdgcn_mfma_f32_16x16x32_bf16(af, bfrag[k], acc, 0, 0, 0);
            }
            #pragma unroll
            for (int r = 0; r < 4; ++r) {
                const float v = acc[r] > 0.f ? acc[r] : 0.f;
                out[(mt * 16 + quad * 4 + r) * OUT_STRIDE + nt * 16 + col] = f2bf(v);
            }
        }
    }
}

// max over the 20 k-rows of each point -> bf16 into cat (non-negative values)
template <int O, int STRIDE>
__device__ __forceinline__ void maxk(const uint16_t* __restrict__ h,
                                     uint16_t* __restrict__ cat_ws, int catoff,
                                     int t, int b, int n0) {
    constexpr int G = O / 8;
    if (t < P * G) {
        const int p = t / G, g = t % G;
        uint16_t mx[8];
        #pragma unroll
        for (int j = 0; j < 8; ++j) mx[j] = 0;
        for (int k = 0; k < KNN; ++k) {
            const uint16_t* row = h + (p * KNN + k) * STRIDE + g * 8;
            #pragma unroll
            for (int j = 0; j < 8; ++j) mx[j] = row[j] > mx[j] ? row[j] : mx[j];
        }
        uint16_t* dst = cat_ws + ((size_t)b * NPTS + n0 + p) * 512 + catoff + g * 8;
        *(short8*)dst = *(const short8*)mx;
    }
}

// ---------------------------------------------------------------------------
// Fused MLP, MFMA edition. Block = 4 points, 256 threads (4 waves).
__global__ __launch_bounds__(256) void fused_mlp_mfma(
    const float* __restrict__ x,
    const int*   __restrict__ idx_ws,
    const float* __restrict__ dist_ws,
    const uint16_t* __restrict__ wf1,
    const uint16_t* __restrict__ wf2,
    const uint16_t* __restrict__ wf3,
    const uint16_t* __restrict__ wf4,
    uint16_t* __restrict__ cat_ws)      // (B*N, 512) bf16
{
    const int n0 = blockIdx.x * P, b = blockIdx.y, t = threadIdx.x;
    const int wave = t >> 6, lane = t & 63;

    __shared__ __align__(16) uint16_t bufA[12800];  // feat(3200) / h2(5760) / slabs(12800)
    __shared__ __align__(16) uint16_t bufB[10880];  // h1(5760) / h3(10880)

    // ---- stage feat: [80][40] bf16, cols 0-2 xc, 3-5 nbr, 6-25 dist, 26+ zero
    for (int i = t; i < 1600; i += 256) ((uint32_t*)bufA)[i] = 0;
    __syncthreads();
    {
        const float* xb = x + (size_t)b * 3 * NPTS;
        if (t < P * KNN) {
            const int p = t / KNN, k = t % KNN;
            const int n = n0 + p;
            const size_t base = ((size_t)b * NPTS + n) * KNN + k;
            const int   m = idx_ws[base];
            const float d = dist_ws[base];
            uint16_t* fr = bufA + t * 40;
            fr[0] = f2bf(xb[n]);        fr[1] = f2bf(xb[NPTS + n]);
            fr[2] = f2bf(xb[2 * NPTS + n]);
            fr[3] = f2bf(xb[m]);        fr[4] = f2bf(xb[NPTS + m]);
            fr[5] = f2bf(xb[2 * NPTS + m]);
            const uint16_t db = f2bf(d);
            #pragma unroll
            for (int j = 0; j < KNN; ++j) bufA[(p * KNN + j) * 40 + 6 + k] = db;
        }
    }
    __syncthreads();

    // ---- L1: feat(A) -> h1(B)
    mfma_layer<4, 1, 40, 72>(bufA, bufB, wf1, wave, lane);
    __syncthreads();

    // ---- L2: h1(B) -> h2(A); x1 = maxk(h1)
    maxk<64, 72>(bufB, cat_ws, 0, t, b, n0);
    mfma_layer<4, 2, 72, 72>(bufB, bufA, wf2, wave, lane);
    __syncthreads();

    // ---- L3: h2(A) -> h3(B); x2 = maxk(h2)
    maxk<64, 72>(bufA, cat_ws, 64, t, b, n0);
    mfma_layer<8, 2, 72, 136>(bufA, bufB, wf3, wave, lane);
    __syncthreads();

    // ---- L4: h3(B) -> per-wave slab (A) -> relu+max -> cat; x3 = maxk(h3)
    maxk<128, 136>(bufB, cat_ws, 128, t, b, n0);
    {
        float* slab = (float*)bufA + wave * 1600;   // [80][20] f32, wave-private
        const int col = lane & 15, quad = lane >> 4;
        #pragma unroll
        for (int ni = 0; ni < 4; ++ni) {
            const int nt = wave * 4 + ni;
            short8 bfrag[4];
            #pragma unroll
            for (int k = 0; k < 4; ++k)
                bfrag[k] = *(const short8*)(wf4 + ((size_t)(nt * 4 + k) * 64 + lane) * 8);
            #pragma unroll
            for (int mt = 0; mt < 5; ++mt) {
                floatx4 acc = {0.f, 0.f, 0.f, 0.f};
                #pragma unroll
                for (int k = 0; k < 4; ++k) {
                    const short8 af = *(const short8*)(bufB + (mt * 16 + col) * 136
                                                           + k * 32 + quad * 8);
                    acc = __builtin_amdgcn_mfma_f32_16x16x32_bf16(af, bfrag[k], acc, 0, 0, 0);
                }
                #pragma unroll
                for (int r = 0; r < 4; ++r)
                    slab[(mt * 16 + quad * 4 + r) * 20 + col] = fmaxf(acc[r], 0.f);
            }
            const int p = lane >> 4, grp = (lane >> 2) & 3, kq = lane & 3;
            floatx4 mx = {0.f, 0.f, 0.f, 0.f};
            #pragma unroll
            for (int i = 0; i < 5; ++i) {
                const floatx4 v = *(const floatx4*)&slab[(p * KNN + kq * 5 + i) * 20 + grp * 4];
                mx[0] = fmaxf(mx[0], v[0]); mx[1] = fmaxf(mx[1], v[1]);
                mx[2] = fmaxf(mx[2], v[2]); mx[3] = fmaxf(mx[3], v[3]);
            }
            #pragma unroll
            for (int r = 0; r < 4; ++r) {
                mx[r] = fmaxf(mx[r], __shfl_xor(mx[r], 1));
                mx[r] = fmaxf(mx[r], __shfl_xor(mx[r], 2));
            }
            if (kq == 0) {
                ushort4v q;
                q.x = f2bf(mx[0]); q.y = f2bf(mx[1]);
                q.z = f2bf(mx[2]); q.w = f2bf(mx[3]);
                uint16_t* dst = cat_ws + ((size_t)b * NPTS + n0 + p) * 512
                              + 256 + nt * 16 + grp * 4;
                *(ushort4v*)dst = q;
            }
        }
    }
}

// ---------------------------------------------------------------------------
// Final GEMM, MFMA: out[b,o,n] = relu( sum_c w5[o,c] * cat[b,n,c] ).
// 64(o) x 64(n) tile, 4 waves (wave = o-subtile), K-chunks of 64.
__global__ __launch_bounds__(256) void final_gemm_mfma(
    const uint16_t* __restrict__ w5b,  // (512,512) bf16 row-major (o,c)
    const uint16_t* __restrict__ cat,  // (B*N,512) bf16
    float* __restrict__ out)           // (B,512,N) f32
{
    const int b  = blockIdx.z;
    const int o0 = blockIdx.y * 64;
    const int n0 = blockIdx.x * 64;
    const int t  = threadIdx.x;
    const int wave = t >> 6, lane = t & 63;
    const int col = lane & 15, quad = lane >> 4;

    __shared__ __align__(16) uint16_t As[64 * 72];  // w5 tile [o][k], +8 pad
    __shared__ __align__(16) uint16_t Bs[64 * 72];  // cat tile [n][k], +8 pad

    floatx4 acc[4] = {{0.f,0.f,0.f,0.f},{0.f,0.f,0.f,0.f},
                      {0.f,0.f,0.f,0.f},{0.f,0.f,0.f,0.f}};

    const size_t arow_base = (size_t)o0 * 512;
    const size_t brow_base = ((size_t)b * NPTS + n0) * 512;

    for (int kc = 0; kc < 512; kc += 64) {
        #pragma unroll
        for (int i = 0; i < 2; ++i) {
            const int idx = t + i * 256;          // 0..511
            const int row = idx >> 3;             // 0..63
            const int k8  = (idx & 7) * 8;        // 0..56
            *(short8*)&As[row * 72 + k8] =
                *(const short8*)&w5b[arow_base + (size_t)row * 512 + kc + k8];
            *(short8*)&Bs[row * 72 + k8] =
                *(const short8*)&cat[brow_base + (size_t)row * 512 + kc + k8];
        }
        __syncthreads();
        #pragma unroll
        for (int kt = 0; kt < 2; ++kt) {
            const short8 af = *(const short8*)&As[(wave * 16 + col) * 72 + kt * 32 + quad * 8];
            #pragma unroll
            for (int ns = 0; ns < 4; ++ns) {
                const short8 bf = *(const short8*)&Bs[(ns * 16 + col) * 72 + kt * 32 + quad * 8];
                acc[ns] = __builtin_amdgcn_mfma_f32_16x16x32_bf16(af, bf, acc[ns], 0, 0, 0);
            }
        }
        __syncthreads();
    }

    #pragma unroll
    for (int ns = 0; ns < 4; ++ns) {
        #pragma unroll
        for (int r = 0; r < 4; ++r) {
            out[((size_t)b * 512 + o0 + wave * 16 + quad * 4 + r) * NPTS
                + n0 + ns * 16 + col] = fmaxf(acc[ns][r], 0.f);
        }
    }
}

// ---------------------------------------------------------------------------
extern "C" void kernel_launch(void* const* d_in, const int* in_sizes, int n_in,
                              void* d_out, int out_size, void* d_ws, size_t ws_size,
                              hipStream_t stream) {
    const float* x  = (const float*)d_in[0];  // (8,3,4096)
    const float* w1 = (const float*)d_in[1];  // (64,26)
    const float* w2 = (const float*)d_in[2];  // (64,64)
    const float* w3 = (const float*)d_in[3];  // (128,64)
    const float* w4 = (const float*)d_in[4];  // (256,128)
    const float* w5 = (const float*)d_in[5];  // (512,512)
    float* out = (float*)d_out;               // (8,512,4096) fp32

    // workspace layout (bytes):
    //   [0)         idx_ws   B*N*K int     = 2,621,440
    //   [2621440)   dist_ws  B*N*K f32     = 2,621,440
    //   [5242880)   cat_ws   B*N*512 bf16  = 33,554,432
    //               (xyzs aliases cat_ws[0:512KB]: consumed by topk BEFORE
    //                fused_mlp writes cat — stream-ordered, safe)
    //   [38797312)  w5b bf16 (512x512)     = 524,288
    //   [72351744)  wf1 4 KB; wf2 8 KB; wf3 16 KB; wf4 64 KB
    char* ws = (char*)d_ws;
    int*      idx_ws  = (int*)ws;
    float*    dist_ws = (float*)(ws + 2621440);
    uint16_t* cat_ws  = (uint16_t*)(ws + 5242880);
    float4*   xyzs    = (float4*)(ws + 5242880);   // alias, 512 KB
    uint16_t* w5b     = (uint16_t*)(ws + 38797312);
    uint16_t* wf1     = (uint16_t*)(ws + 72351744);
    uint16_t* wf2     = (uint16_t*)(ws + 72351744 + 4096);
    uint16_t* wf3     = (uint16_t*)(ws + 72351744 + 4096 + 8192);
    uint16_t* wf4     = (uint16_t*)(ws + 72351744 + 4096 + 8192 + 16384);

    prep_wfrag<<<dim3(1), 256, 0, stream>>>(w1, wf1, 26,  4, 1);
    prep_wfrag<<<dim3(2), 256, 0, stream>>>(w2, wf2, 64,  4, 2);
    prep_wfrag<<<dim3(4), 256, 0, stream>>>(w3, wf3, 64,  8, 2);
    prep_wfrag<<<dim3(16), 256, 0, stream>>>(w4, wf4, 128, 16, 4);
    prep_w5bf<<<dim3(1024), 256, 0, stream>>>(w5, w5b);
    prep_xyzs<<<dim3((NB * NPTS + 255) / 256), 256, 0, stream>>>(x, xyzs);

    topk_kernel<<<dim3(NPTS / 4, NB), 256, 0, stream>>>(xyzs, idx_ws, dist_ws);
    fused_mlp_mfma<<<dim3(NPTS / P, NB), 256, 0, stream>>>(
        x, idx_ws, dist_ws, wf1, wf2, wf3, wf4, cat_ws);
    final_gemm_mfma<<<dim3(NPTS / 64, 512 / 64, NB), 256, 0, stream>>>(w5b, cat_ws, out);
}

// Round 5
// 395.395 us; speedup vs baseline: 5.0585x; 1.0416x over previous
//
#include <hip/hip_runtime.h>
#include <cstdint>
#include <cstddef>

#define NB   8
#define NPTS 4096
#define KNN  20
#define P    4   // points per fused-MLP block (M = P*KNN = 80 rows = 5 m-tiles)

typedef __attribute__((ext_vector_type(8))) short    short8;
typedef __attribute__((ext_vector_type(4))) float    floatx4;
typedef __attribute__((ext_vector_type(4))) unsigned short ushort4v;

__device__ __forceinline__ uint16_t f2bf(float f) {
    uint32_t u = __float_as_uint(f);
    uint32_t r = (u + 0x7FFFu + ((u >> 16) & 1u)) >> 16;   // RNE
    return (uint16_t)r;
}
__device__ __forceinline__ float bf2f(uint16_t h) {
    return __uint_as_float(((uint32_t)h) << 16);
}

// ordered-float transform: monotone fp32 -> uint32 (no NaNs present)
__device__ __forceinline__ uint32_t f2ord(float v) {
    uint32_t u = __float_as_uint(v);
    uint32_t m = (uint32_t)((int32_t)u >> 31) | 0x80000000u;
    return u ^ m;
}

// compare-swap keeping larger in a
__device__ __forceinline__ void cs_u64(unsigned long long& a, unsigned long long& b) {
    unsigned long long hi = a > b ? a : b;
    unsigned long long lo = a > b ? b : a;
    a = hi; b = lo;
}

// DPP move of a u64 (2x b32), invalid lanes read 0 (= -inf for unsigned keys)
template <int CTRL>
__device__ __forceinline__ unsigned long long dpp_mov_u64(unsigned long long v) {
    int lo = __builtin_amdgcn_update_dpp(0, (int)(uint32_t)v,         CTRL, 0xF, 0xF, true);
    int hi = __builtin_amdgcn_update_dpp(0, (int)(uint32_t)(v >> 32), CTRL, 0xF, 0xF, true);
    return ((unsigned long long)(uint32_t)hi << 32) | (uint32_t)lo;
}

// wave64 max-reduce via DPP (no LDS): result broadcast to all lanes via readlane
__device__ __forceinline__ unsigned long long wave_max_u64(unsigned long long v) {
    unsigned long long o;
    o = dpp_mov_u64<0x111>(v); v = o > v ? o : v;   // row_shr:1
    o = dpp_mov_u64<0x112>(v); v = o > v ? o : v;   // row_shr:2
    o = dpp_mov_u64<0x114>(v); v = o > v ? o : v;   // row_shr:4
    o = dpp_mov_u64<0x118>(v); v = o > v ? o : v;   // row_shr:8
    o = dpp_mov_u64<0x142>(v); v = o > v ? o : v;   // row_bcast:15
    o = dpp_mov_u64<0x143>(v); v = o > v ? o : v;   // row_bcast:31 -> lane 63 has max
    uint32_t lo = (uint32_t)__builtin_amdgcn_readlane((int)(uint32_t)v, 63);
    uint32_t hi = (uint32_t)__builtin_amdgcn_readlane((int)(uint32_t)(v >> 32), 63);
    return ((unsigned long long)hi << 32) | lo;
}

// ---------------------------------------------------------------------------
// Prep: pack (x,y,z,||x||^2) per point; sq uses the SAME fma order as the
// pair formula everywhere -> bitwise-identical pair values to prior rounds.
__global__ __launch_bounds__(256) void prep_xyzs(
    const float* __restrict__ x,      // (B,3,N)
    float4* __restrict__ xyzs)        // (B,N)
{
    const int i = blockIdx.x * 256 + threadIdx.x;
    if (i >= NB * NPTS) return;
    const int b = i / NPTS, n = i - b * NPTS;
    const float* xb = x + (size_t)b * 3 * NPTS;
    const float x0 = xb[n], x1 = xb[NPTS + n], x2 = xb[2 * NPTS + n];
    float4 v;
    v.x = x0; v.y = x1; v.z = x2;
    v.w = fmaf(x2, x2, fmaf(x1, x1, x0 * x0));
    xyzs[i] = v;
}

// ---------------------------------------------------------------------------
// Top-20 selection: one wave per point, lane l owns columns m%64==l.
// Lane-local register top-3 + rare refill; per-round winner via DPP reduce.
__global__ __launch_bounds__(256) void topk_kernel(
    const float4* __restrict__ xyzs,  // (B,N) packed
    int*   __restrict__ idx_out,      // (B,N,K)
    float* __restrict__ dist_out)     // (B,N,K)
{
    const int t = threadIdx.x;
    const int wave = t >> 6, l = t & 63;
    const int n = blockIdx.x * 4 + wave;
    const int b = blockIdx.y;
    const float4* xq = xyzs + (size_t)b * NPTS;

    const float4 pn = xq[n];
    const float xn0 = pn.x, xn1 = pn.y, xn2 = pn.z, sqn = pn.w;

    unsigned long long L0 = 0ull, L1 = 0ull, L2 = 0ull;
    unsigned long long consumed = 0ull;

    for (int j = 0; j < 64; ++j) {
        const int m = j * 64 + l;
        const float4 pm = xq[m];
        const float dot = fmaf(xn2, pm.z, fmaf(xn1, pm.y, xn0 * pm.x));
        const float pair = 2.0f * dot - sqn - pm.w;
        const unsigned long long key =
            ((unsigned long long)f2ord(pair) << 32) | (uint32_t)(NPTS - 1 - m);
        if (key > L2) { L2 = key; cs_u64(L1, L2); cs_u64(L0, L1); }
    }

    int my_m = 0;
    for (int k = 0; k < KNN; ++k) {
        if (L0 == 0ull) {  // rare refill: rebuild top-3 of unconsumed columns
            L1 = 0ull; L2 = 0ull;
            for (int j = 0; j < 64; ++j) {
                if ((consumed >> j) & 1ull) continue;
                const int m = j * 64 + l;
                const float4 pm = xq[m];
                const float dot = fmaf(xn2, pm.z, fmaf(xn1, pm.y, xn0 * pm.x));
                const float pair = 2.0f * dot - sqn - pm.w;
                const unsigned long long key =
                    ((unsigned long long)f2ord(pair) << 32) | (uint32_t)(NPTS - 1 - m);
                if (key > L2) { L2 = key; cs_u64(L1, L2); cs_u64(L0, L1); }
            }
        }
        const unsigned long long w = wave_max_u64(L0);
        const int m = (NPTS - 1) - (int)(w & 0xFFFFFFFFull);
        if (l == k) my_m = m;
        if ((m & 63) == l) {           // owner pops its head
            L0 = L1; L1 = L2; L2 = 0ull;
            consumed |= 1ull << (m >> 6);
        }
    }

    if (l < KNN) {
        const float4 pm = xq[my_m];
        const float d0 = pm.x - xn0, d1 = pm.y - xn1, d2 = pm.z - xn2;
        const float dist = sqrtf(((d0 * d0 + d1 * d1) + d2 * d2) + 1e-12f);
        const size_t base = ((size_t)b * NPTS + n) * KNN + l;
        idx_out[base]  = my_m;
        dist_out[base] = dist;
    }
}

// ---------------------------------------------------------------------------
// Weight prep: fragment-ordered bf16 B-operands for mfma_f32_16x16x32_bf16.
__global__ void prep_wfrag(const float* __restrict__ w, uint16_t* __restrict__ frag,
                           int C, int NT, int KT) {
    const int i = blockIdx.x * 256 + threadIdx.x;   // one (nt,kt,lane)
    if (i >= NT * KT * 64) return;
    const int lane = i & 63;
    const int kt   = (i >> 6) % KT;
    const int nt   = (i >> 6) / KT;
    const int n    = nt * 16 + (lane & 15);
    const int c0   = kt * 32 + (lane >> 4) * 8;
    uint16_t o[8];
    #pragma unroll
    for (int j = 0; j < 8; ++j) {
        const int c = c0 + j;
        o[j] = (c < C) ? f2bf(w[(size_t)n * C + c]) : (uint16_t)0;
    }
    uint16_t* dst = frag + (size_t)i * 8;
    #pragma unroll
    for (int j = 0; j < 8; ++j) dst[j] = o[j];
}

// w5 (512,512) fp32 -> bf16 row-major
__global__ __launch_bounds__(256) void prep_w5bf(const float* __restrict__ w5,
                                                 uint16_t* __restrict__ w5b) {
    const int i = blockIdx.x * 256 + threadIdx.x;
    if (i < 512 * 512) w5b[i] = f2bf(w5[i]);
}

// ---------------------------------------------------------------------------
// One MFMA conv layer: in (LDS bf16, [80][IN_STRIDE]) x wf -> out (LDS bf16,
// [80][OUT_STRIDE], relu'd). NT_TOT n-tiles split over 4 waves.
template <int NT_TOT, int KT, int IN_STRIDE, int OUT_STRIDE>
__device__ __forceinline__ void mfma_layer(const uint16_t* __restrict__ in,
                                           uint16_t* __restrict__ out,
                                           const uint16_t* __restrict__ wf,
                                           int wave, int lane) {
    constexpr int NT_W = NT_TOT / 4;
    const int col = lane & 15, quad = lane >> 4;
    #pragma unroll
    for (int ni = 0; ni < NT_W; ++ni) {
        const int nt = wave * NT_W + ni;
        short8 bfrag[KT];
        #pragma unroll
        for (int k = 0; k < KT; ++k)
            bfrag[k] = *(const short8*)(wf + ((size_t)(nt * KT + k) * 64 + lane) * 8);
        #pragma unroll
        for (int mt = 0; mt < 5; ++mt) {
            floatx4 acc = {0.f, 0.f, 0.f, 0.f};
            #pragma unroll
            for (int k = 0; k < KT; ++k) {
                const short8 af = *(const short8*)(in + (mt * 16 + col) * IN_STRIDE
                                                      + k * 32 + quad * 8);
                acc = __builtin_amdgcn_mfma_f32_16x16x32_bf16(af, bfrag[k], acc, 0, 0, 0);
            }
            #pragma unroll
            for (int r = 0; r < 4; ++r) {
                const float v = acc[r] > 0.f ? acc[r] : 0.f;
                out[(mt * 16 + quad * 4 + r) * OUT_STRIDE + nt * 16 + col] = f2bf(v);
            }
        }
    }
}

// max over the 20 k-rows of each point -> bf16 into cat (non-negative values)
template <int O, int STRIDE>
__device__ __forceinline__ void maxk(const uint16_t* __restrict__ h,
                                     uint16_t* __restrict__ cat_ws, int catoff,
                                     int t, int b, int n0) {
    constexpr int G = O / 8;
    if (t < P * G) {
        const int p = t / G, g = t % G;
        uint16_t mx[8];
        #pragma unroll
        for (int j = 0; j < 8; ++j) mx[j] = 0;
        for (int k = 0; k < KNN; ++k) {
            const uint16_t* row = h + (p * KNN + k) * STRIDE + g * 8;
            #pragma unroll
            for (int j = 0; j < 8; ++j) mx[j] = row[j] > mx[j] ? row[j] : mx[j];
        }
        uint16_t* dst = cat_ws + ((size_t)b * NPTS + n0 + p) * 512 + catoff + g * 8;
        *(short8*)dst = *(const short8*)mx;
    }
}

// ---------------------------------------------------------------------------
// Fused MLP, MFMA edition. Block = 4 points, 256 threads (4 waves).
__global__ __launch_bounds__(256) void fused_mlp_mfma(
    const float* __restrict__ x,
    const int*   __restrict__ idx_ws,
    const float* __restrict__ dist_ws,
    const uint16_t* __restrict__ wf1,
    const uint16_t* __restrict__ wf2,
    const uint16_t* __restrict__ wf3,
    const uint16_t* __restrict__ wf4,
    uint16_t* __restrict__ cat_ws)      // (B*N, 512) bf16
{
    const int n0 = blockIdx.x * P, b = blockIdx.y, t = threadIdx.x;
    const int wave = t >> 6, lane = t & 63;

    __shared__ __align__(16) uint16_t bufA[12800];  // feat(3200) / h2(5760) / slabs(12800)
    __shared__ __align__(16) uint16_t bufB[10880];  // h1(5760) / h3(10880)

    // ---- stage feat: [80][40] bf16, cols 0-2 xc, 3-5 nbr, 6-25 dist, 26+ zero
    for (int i = t; i < 1600; i += 256) ((uint32_t*)bufA)[i] = 0;
    __syncthreads();
    {
        const float* xb = x + (size_t)b * 3 * NPTS;
        if (t < P * KNN) {
            const int p = t / KNN, k = t % KNN;
            const int n = n0 + p;
            const size_t base = ((size_t)b * NPTS + n) * KNN + k;
            const int   m = idx_ws[base];
            const float d = dist_ws[base];
            uint16_t* fr = bufA + t * 40;
            fr[0] = f2bf(xb[n]);        fr[1] = f2bf(xb[NPTS + n]);
            fr[2] = f2bf(xb[2 * NPTS + n]);
            fr[3] = f2bf(xb[m]);        fr[4] = f2bf(xb[NPTS + m]);
            fr[5] = f2bf(xb[2 * NPTS + m]);
            const uint16_t db = f2bf(d);
            #pragma unroll
            for (int j = 0; j < KNN; ++j) bufA[(p * KNN + j) * 40 + 6 + k] = db;
        }
    }
    __syncthreads();

    // ---- L1: feat(A) -> h1(B)
    mfma_layer<4, 1, 40, 72>(bufA, bufB, wf1, wave, lane);
    __syncthreads();

    // ---- L2: h1(B) -> h2(A); x1 = maxk(h1)
    maxk<64, 72>(bufB, cat_ws, 0, t, b, n0);
    mfma_layer<4, 2, 72, 72>(bufB, bufA, wf2, wave, lane);
    __syncthreads();

    // ---- L3: h2(A) -> h3(B); x2 = maxk(h2)
    maxk<64, 72>(bufA, cat_ws, 64, t, b, n0);
    mfma_layer<8, 2, 72, 136>(bufA, bufB, wf3, wave, lane);
    __syncthreads();

    // ---- L4: h3(B) -> per-wave slab (A) -> relu+max -> cat; x3 = maxk(h3)
    maxk<128, 136>(bufB, cat_ws, 128, t, b, n0);
    {
        float* slab = (float*)bufA + wave * 1600;   // [80][20] f32, wave-private
        const int col = lane & 15, quad = lane >> 4;
        #pragma unroll
        for (int ni = 0; ni < 4; ++ni) {
            const int nt = wave * 4 + ni;
            short8 bfrag[4];
            #pragma unroll
            for (int k = 0; k < 4; ++k)
                bfrag[k] = *(const short8*)(wf4 + ((size_t)(nt * 4 + k) * 64 + lane) * 8);
            #pragma unroll
            for (int mt = 0; mt < 5; ++mt) {
                floatx4 acc = {0.f, 0.f, 0.f, 0.f};
                #pragma unroll
                for (int k = 0; k < 4; ++k) {
                    const short8 af = *(const short8*)(bufB + (mt * 16 + col) * 136
                                                           + k * 32 + quad * 8);
                    acc = __builtin_amdgcn_mfma_f32_16x16x32_bf16(af, bfrag[k], acc, 0, 0, 0);
                }
                #pragma unroll
                for (int r = 0; r < 4; ++r)
                    slab[(mt * 16 + quad * 4 + r) * 20 + col] = fmaxf(acc[r], 0.f);
            }
            const int p = lane >> 4, grp = (lane >> 2) & 3, kq = lane & 3;
            floatx4 mx = {0.f, 0.f, 0.f, 0.f};
            #pragma unroll
            for (int i = 0; i < 5; ++i) {
                const floatx4 v = *(const floatx4*)&slab[(p * KNN + kq * 5 + i) * 20 + grp * 4];
                mx[0] = fmaxf(mx[0], v[0]); mx[1] = fmaxf(mx[1], v[1]);
                mx[2] = fmaxf(mx[2], v[2]); mx[3] = fmaxf(mx[3], v[3]);
            }
            #pragma unroll
            for (int r = 0; r < 4; ++r) {
                mx[r] = fmaxf(mx[r], __shfl_xor(mx[r], 1));
                mx[r] = fmaxf(mx[r], __shfl_xor(mx[r], 2));
            }
            if (kq == 0) {
                ushort4v q;
                q.x = f2bf(mx[0]); q.y = f2bf(mx[1]);
                q.z = f2bf(mx[2]); q.w = f2bf(mx[3]);
                uint16_t* dst = cat_ws + ((size_t)b * NPTS + n0 + p) * 512
                              + 256 + nt * 16 + grp * 4;
                *(ushort4v*)dst = q;
            }
        }
    }
}

// ---------------------------------------------------------------------------
// Final GEMM, MFMA: out[b,o,n] = relu( sum_c w5[o,c] * cat[b,n,c] ).
// 64(o) x 64(n) tile, 4 waves (wave = o-subtile), K-chunks of 64.
__global__ __launch_bounds__(256) void final_gemm_mfma(
    const uint16_t* __restrict__ w5b,  // (512,512) bf16 row-major (o,c)
    const uint16_t* __restrict__ cat,  // (B*N,512) bf16
    float* __restrict__ out)           // (B,512,N) f32
{
    const int b  = blockIdx.z;
    const int o0 = blockIdx.y * 64;
    const int n0 = blockIdx.x * 64;
    const int t  = threadIdx.x;
    const int wave = t >> 6, lane = t & 63;
    const int col = lane & 15, quad = lane >> 4;

    __shared__ __align__(16) uint16_t As[64 * 72];  // w5 tile [o][k], +8 pad
    __shared__ __align__(16) uint16_t Bs[64 * 72];  // cat tile [n][k], +8 pad

    floatx4 acc[4] = {{0.f,0.f,0.f,0.f},{0.f,0.f,0.f,0.f},
                      {0.f,0.f,0.f,0.f},{0.f,0.f,0.f,0.f}};

    const size_t arow_base = (size_t)o0 * 512;
    const size_t brow_base = ((size_t)b * NPTS + n0) * 512;

    for (int kc = 0; kc < 512; kc += 64) {
        #pragma unroll
        for (int i = 0; i < 2; ++i) {
            const int idx = t + i * 256;          // 0..511
            const int row = idx >> 3;             // 0..63
            const int k8  = (idx & 7) * 8;        // 0..56
            *(short8*)&As[row * 72 + k8] =
                *(const short8*)&w5b[arow_base + (size_t)row * 512 + kc + k8];
            *(short8*)&Bs[row * 72 + k8] =
                *(const short8*)&cat[brow_base + (size_t)row * 512 + kc + k8];
        }
        __syncthreads();
        #pragma unroll
        for (int kt = 0; kt < 2; ++kt) {
            const short8 af = *(const short8*)&As[(wave * 16 + col) * 72 + kt * 32 + quad * 8];
            #pragma unroll
            for (int ns = 0; ns < 4; ++ns) {
                const short8 bf = *(const short8*)&Bs[(ns * 16 + col) * 72 + kt * 32 + quad * 8];
                acc[ns] = __builtin_amdgcn_mfma_f32_16x16x32_bf16(af, bf, acc[ns], 0, 0, 0);
            }
        }
        __syncthreads();
    }

    #pragma unroll
    for (int ns = 0; ns < 4; ++ns) {
        #pragma unroll
        for (int r = 0; r < 4; ++r) {
            out[((size_t)b * 512 + o0 + wave * 16 + quad * 4 + r) * NPTS
                + n0 + ns * 16 + col] = fmaxf(acc[ns][r], 0.f);
        }
    }
}

// ---------------------------------------------------------------------------
extern "C" void kernel_launch(void* const* d_in, const int* in_sizes, int n_in,
                              void* d_out, int out_size, void* d_ws, size_t ws_size,
                              hipStream_t stream) {
    const float* x  = (const float*)d_in[0];  // (8,3,4096)
    const float* w1 = (const float*)d_in[1];  // (64,26)
    const float* w2 = (const float*)d_in[2];  // (64,64)
    const float* w3 = (const float*)d_in[3];  // (128,64)
    const float* w4 = (const float*)d_in[4];  // (256,128)
    const float* w5 = (const float*)d_in[5];  // (512,512)
    float* out = (float*)d_out;               // (8,512,4096) fp32

    // workspace layout (bytes):
    //   [0)         idx_ws   B*N*K int     = 2,621,440
    //   [2621440)   dist_ws  B*N*K f32     = 2,621,440
    //   [5242880)   cat_ws   B*N*512 bf16  = 33,554,432
    //               (xyzs aliases cat_ws[0:512KB]: consumed by topk BEFORE
    //                fused_mlp writes cat — stream-ordered, safe)
    //   [38797312)  w5b bf16 (512x512)     = 524,288
    //   [72351744)  wf1 4 KB; wf2 8 KB; wf3 16 KB; wf4 64 KB
    char* ws = (char*)d_ws;
    int*      idx_ws  = (int*)ws;
    float*    dist_ws = (float*)(ws + 2621440);
    uint16_t* cat_ws  = (uint16_t*)(ws + 5242880);
    float4*   xyzs    = (float4*)(ws + 5242880);   // alias, 512 KB
    uint16_t* w5b     = (uint16_t*)(ws + 38797312);
    uint16_t* wf1     = (uint16_t*)(ws + 72351744);
    uint16_t* wf2     = (uint16_t*)(ws + 72351744 + 4096);
    uint16_t* wf3     = (uint16_t*)(ws + 72351744 + 4096 + 8192);
    uint16_t* wf4     = (uint16_t*)(ws + 72351744 + 4096 + 8192 + 16384);

    prep_wfrag<<<dim3(1), 256, 0, stream>>>(w1, wf1, 26,  4, 1);
    prep_wfrag<<<dim3(2), 256, 0, stream>>>(w2, wf2, 64,  4, 2);
    prep_wfrag<<<dim3(4), 256, 0, stream>>>(w3, wf3, 64,  8, 2);
    prep_wfrag<<<dim3(16), 256, 0, stream>>>(w4, wf4, 128, 16, 4);
    prep_w5bf<<<dim3(1024), 256, 0, stream>>>(w5, w5b);
    prep_xyzs<<<dim3((NB * NPTS + 255) / 256), 256, 0, stream>>>(x, xyzs);

    topk_kernel<<<dim3(NPTS / 4, NB), 256, 0, stream>>>(xyzs, idx_ws, dist_ws);
    fused_mlp_mfma<<<dim3(NPTS / P, NB), 256, 0, stream>>>(
        x, idx_ws, dist_ws, wf1, wf2, wf3, wf4, cat_ws);
    final_gemm_mfma<<<dim3(NPTS / 64, 512 / 64, NB), 256, 0, stream>>>(w5b, cat_ws, out);
}

// Round 7
// 381.450 us; speedup vs baseline: 5.2434x; 1.0366x over previous
//
#include <hip/hip_runtime.h>
#include <cstdint>
#include <cstddef>

#define NB   8
#define NPTS 4096
#define KNN  20
#define P    4   // points per fused-MLP block (M = P*KNN = 80 rows = 5 m-tiles)

typedef __attribute__((ext_vector_type(8))) short    short8;
typedef __attribute__((ext_vector_type(4))) float    floatx4;
typedef __attribute__((ext_vector_type(4))) unsigned short ushort4v;

__device__ __forceinline__ uint16_t f2bf(float f) {
    uint32_t u = __float_as_uint(f);
    uint32_t r = (u + 0x7FFFu + ((u >> 16) & 1u)) >> 16;   // RNE
    return (uint16_t)r;
}
__device__ __forceinline__ float bf2f(uint16_t h) {
    return __uint_as_float(((uint32_t)h) << 16);
}

#define NEGINF __int_as_float((int)0xFF800000)

// median of three floats (no NaNs) -> v_med3_f32 / min-max triplet
__device__ __forceinline__ float med3f(float a, float b, float c) {
    return fmaxf(fminf(a, b), fminf(fmaxf(a, b), c));
}

// DPP f32 max step: invalid source lanes fall back to own value (idempotent)
template <int CTRL>
__device__ __forceinline__ float dpp_maxf(float v) {
    int o = __builtin_amdgcn_update_dpp(__float_as_int(v), __float_as_int(v),
                                        CTRL, 0xF, 0xF, false);
    return fmaxf(v, __int_as_float(o));
}
// wave64 f32 max-reduce, result broadcast via readlane 63
__device__ __forceinline__ float wave_max_f32(float v) {
    v = dpp_maxf<0x111>(v);   // row_shr:1
    v = dpp_maxf<0x112>(v);   // row_shr:2
    v = dpp_maxf<0x114>(v);   // row_shr:4
    v = dpp_maxf<0x118>(v);   // row_shr:8
    v = dpp_maxf<0x142>(v);   // row_bcast:15
    v = dpp_maxf<0x143>(v);   // row_bcast:31 -> lane 63 has max
    return __int_as_float(__builtin_amdgcn_readlane(__float_as_int(v), 63));
}

// ---------------------------------------------------------------------------
// Prep: pack (x,y,z,||x||^2); sq uses the SAME fma order as rounds 1-5 so
// pair values are bitwise-identical to the passing kernels.
__global__ __launch_bounds__(256) void prep_xyzs(
    const float* __restrict__ x,      // (B,3,N)
    float4* __restrict__ xyzs)        // (B,N)
{
    const int i = blockIdx.x * 256 + threadIdx.x;
    if (i >= NB * NPTS) return;
    const int b = i / NPTS, n = i - b * NPTS;
    const float* xb = x + (size_t)b * 3 * NPTS;
    const float x0 = xb[n], x1 = xb[NPTS + n], x2 = xb[2 * NPTS + n];
    float4 v;
    v.x = x0; v.y = x1; v.z = x2;
    v.w = fmaf(x2, x2, fmaf(x1, x1, x0 * x0));
    xyzs[i] = v;
}

// ---------------------------------------------------------------------------
// Top-20: one wave per point, lane l owns columns m%64==l (m = j*64+l).
// Full-precision f32 pair values (bitwise == rounds 1-5). Lane-local sorted
// top-3 values V0>=V1>=V2 (med3 insert) + parallel index regs J0..J2 holding
// j. Per-round winner via DPP f32 max + ballot; rare refill on >3 pops.
__global__ __launch_bounds__(256) void topk_kernel(
    const float4* __restrict__ xyzs,  // (B,N) packed (x,y,z,sq)
    int*   __restrict__ idx_out,      // (B,N,K)
    float* __restrict__ dist_out)     // (B,N,K)
{
    const int t = threadIdx.x;
    const int wave = t >> 6, l = t & 63;
    const int n = blockIdx.x * 4 + wave;
    const int b = blockIdx.y;
    const float4* xq = xyzs + (size_t)b * NPTS;

    const float4 pn = xq[n];
    const float xn0 = pn.x, xn1 = pn.y, xn2 = pn.z, sqn = pn.w;

    float V0 = NEGINF, V1 = NEGINF, V2 = NEGINF;
    int   J0 = 0,      J1 = 0,      J2 = 0;
    unsigned long long consumed = 0ull;

    #pragma unroll 8
    for (int j = 0; j < 64; ++j) {
        const float4 pm = xq[j * 64 + l];
        const float dot = fmaf(xn2, pm.z, fmaf(xn1, pm.y, xn0 * pm.x));
        const float s = 2.0f * dot - sqn - pm.w;      // == rounds 1-5 bitwise
        const bool c0 = s > V0, c1 = s > V1, c2 = s > V2;
        const float nV2 = med3f(V1, V2, s);
        const float nV1 = med3f(V0, V1, s);
        V0 = fmaxf(V0, s);
        V1 = nV1; V2 = nV2;
        const int tA = c1 ? J1 : j;
        J2 = c2 ? tA : J2;
        const int tB = c0 ? J0 : j;
        J1 = c1 ? tB : J1;
        J0 = c0 ? j : J0;
    }

    int my_m = 0;
    for (int k = 0; k < KNN; ++k) {
        if (V0 == NEGINF) {   // rare refill: rebuild top-3 of unconsumed cols
            V1 = NEGINF; V2 = NEGINF;
            for (int j = 0; j < 64; ++j) {
                const float4 pm = xq[j * 64 + l];
                const float dot = fmaf(xn2, pm.z, fmaf(xn1, pm.y, xn0 * pm.x));
                float s = 2.0f * dot - sqn - pm.w;
                if ((consumed >> j) & 1ull) s = NEGINF;
                const bool c0 = s > V0, c1 = s > V1, c2 = s > V2;
                const float nV2 = med3f(V1, V2, s);
                const float nV1 = med3f(V0, V1, s);
                V0 = fmaxf(V0, s);
                V1 = nV1; V2 = nV2;
                const int tA = c1 ? J1 : j;
                J2 = c2 ? tA : J2;
                const int tB = c0 ? J0 : j;
                J1 = c1 ? tB : J1;
                J0 = c0 ? j : J0;
            }
        }
        const float w = wave_max_f32(V0);
        const unsigned long long own = __ballot(V0 == w);
        const int owner = (int)__builtin_ctzll(own);
        const int jwin  = __builtin_amdgcn_readlane(J0, owner);
        const int m     = jwin * 64 + owner;
        if (l == k) my_m = m;
        if (l == owner) {                 // owner pops its head
            consumed |= 1ull << J0;
            V0 = V1; V1 = V2; V2 = NEGINF;
            J0 = J1; J1 = J2;
        }
    }

    if (l < KNN) {
        const float4 pm = xq[my_m];
        const float d0 = pm.x - xn0, d1 = pm.y - xn1, d2 = pm.z - xn2;
        const float dist = sqrtf(((d0 * d0 + d1 * d1) + d2 * d2) + 1e-12f);
        const size_t base = ((size_t)b * NPTS + n) * KNN + l;
        idx_out[base]  = my_m;
        dist_out[base] = dist;
    }
}

// ---------------------------------------------------------------------------
// Weight prep: fragment-ordered bf16 B-operands for mfma_f32_16x16x32_bf16.
__global__ void prep_wfrag(const float* __restrict__ w, uint16_t* __restrict__ frag,
                           int C, int NT, int KT) {
    const int i = blockIdx.x * 256 + threadIdx.x;   // one (nt,kt,lane)
    if (i >= NT * KT * 64) return;
    const int lane = i & 63;
    const int kt   = (i >> 6) % KT;
    const int nt   = (i >> 6) / KT;
    const int n    = nt * 16 + (lane & 15);
    const int c0   = kt * 32 + (lane >> 4) * 8;
    uint16_t o[8];
    #pragma unroll
    for (int j = 0; j < 8; ++j) {
        const int c = c0 + j;
        o[j] = (c < C) ? f2bf(w[(size_t)n * C + c]) : (uint16_t)0;
    }
    uint16_t* dst = frag + (size_t)i * 8;
    #pragma unroll
    for (int j = 0; j < 8; ++j) dst[j] = o[j];
}

// w5 (512,512) fp32 -> bf16 row-major
__global__ __launch_bounds__(256) void prep_w5bf(const float* __restrict__ w5,
                                                 uint16_t* __restrict__ w5b) {
    const int i = blockIdx.x * 256 + threadIdx.x;
    if (i < 512 * 512) w5b[i] = f2bf(w5[i]);
}

// ---------------------------------------------------------------------------
// One MFMA conv layer: in (LDS bf16, [80][IN_STRIDE]) x wf -> out (LDS bf16,
// [80][OUT_STRIDE], relu'd). bfrag preloaded for all ni; af hoisted out of
// the ni loop (one A-read per (mt,kt), reused across NT_W n-tiles).
template <int NT_TOT, int KT, int IN_STRIDE, int OUT_STRIDE>
__device__ __forceinline__ void mfma_layer(const uint16_t* __restrict__ in,
                                           uint16_t* __restrict__ out,
                                           const uint16_t* __restrict__ wf,
                                           int wave, int lane) {
    constexpr int NT_W = NT_TOT / 4;
    const int col = lane & 15, quad = lane >> 4;
    short8 bfrag[NT_W][KT];
    #pragma unroll
    for (int ni = 0; ni < NT_W; ++ni)
        #pragma unroll
        for (int k = 0; k < KT; ++k)
            bfrag[ni][k] = *(const short8*)(wf +
                ((size_t)((wave * NT_W + ni) * KT + k) * 64 + lane) * 8);
    #pragma unroll
    for (int mt = 0; mt < 5; ++mt) {
        short8 af[KT];
        #pragma unroll
        for (int k = 0; k < KT; ++k)
            af[k] = *(const short8*)(in + (mt * 16 + col) * IN_STRIDE + k * 32 + quad * 8);
        #pragma unroll
        for (int ni = 0; ni < NT_W; ++ni) {
            floatx4 acc = {0.f, 0.f, 0.f, 0.f};
            #pragma unroll
            for (int k = 0; k < KT; ++k)
                acc = __builtin_amdgcn_mfma_f32_16x16x32_bf16(af[k], bfrag[ni][k], acc, 0, 0, 0);
            const int nt = wave * NT_W + ni;
            #pragma unroll
            for (int r = 0; r < 4; ++r) {
                const float v = acc[r] > 0.f ? acc[r] : 0.f;
                out[(mt * 16 + quad * 4 + r) * OUT_STRIDE + nt * 16 + col] = f2bf(v);
            }
        }
    }
}

// max over the 20 k-rows of each point -> bf16 into cat (non-negative values)
template <int O, int STRIDE>
__device__ __forceinline__ void maxk(const uint16_t* __restrict__ h,
                                     uint16_t* __restrict__ cat_ws, int catoff,
                                     int t, int b, int n0) {
    constexpr int G = O / 8;
    if (t < P * G) {
        const int p = t / G, g = t % G;
        uint16_t mx[8];
        #pragma unroll
        for (int j = 0; j < 8; ++j) mx[j] = 0;
        for (int k = 0; k < KNN; ++k) {
            const uint16_t* row = h + (p * KNN + k) * STRIDE + g * 8;
            #pragma unroll
            for (int j = 0; j < 8; ++j) mx[j] = row[j] > mx[j] ? row[j] : mx[j];
        }
        uint16_t* dst = cat_ws + ((size_t)b * NPTS + n0 + p) * 512 + catoff + g * 8;
        *(short8*)dst = *(const short8*)mx;
    }
}

// ---------------------------------------------------------------------------
// Fused MLP, MFMA edition. Block = 4 points, 256 threads (4 waves).
__global__ __launch_bounds__(256) void fused_mlp_mfma(
    const float* __restrict__ x,
    const int*   __restrict__ idx_ws,
    const float* __restrict__ dist_ws,
    const uint16_t* __restrict__ wf1,
    const uint16_t* __restrict__ wf2,
    const uint16_t* __restrict__ wf3,
    const uint16_t* __restrict__ wf4,
    uint16_t* __restrict__ cat_ws)      // (B*N, 512) bf16
{
    const int n0 = blockIdx.x * P, b = blockIdx.y, t = threadIdx.x;
    const int wave = t >> 6, lane = t & 63;

    __shared__ __align__(16) uint16_t bufA[12800];  // feat(3200) / h2(5760) / slabs(12800)
    __shared__ __align__(16) uint16_t bufB[10880];  // h1(5760) / h3(10880)

    // ---- stage feat: [80][40] bf16, cols 0-2 xc, 3-5 nbr, 6-25 dist, 26+ zero
    for (int i = t; i < 1600; i += 256) ((uint32_t*)bufA)[i] = 0;
    __syncthreads();
    {
        const float* xb = x + (size_t)b * 3 * NPTS;
        if (t < P * KNN) {
            const int p = t / KNN, k = t % KNN;
            const int n = n0 + p;
            const size_t base = ((size_t)b * NPTS + n) * KNN + k;
            const int   m = idx_ws[base];
            const float d = dist_ws[base];
            uint16_t* fr = bufA + t * 40;
            fr[0] = f2bf(xb[n]);        fr[1] = f2bf(xb[NPTS + n]);
            fr[2] = f2bf(xb[2 * NPTS + n]);
            fr[3] = f2bf(xb[m]);        fr[4] = f2bf(xb[NPTS + m]);
            fr[5] = f2bf(xb[2 * NPTS + m]);
            const uint16_t db = f2bf(d);
            #pragma unroll
            for (int j = 0; j < KNN; ++j) bufA[(p * KNN + j) * 40 + 6 + k] = db;
        }
    }
    __syncthreads();

    // ---- L1: feat(A) -> h1(B)
    mfma_layer<4, 1, 40, 72>(bufA, bufB, wf1, wave, lane);
    __syncthreads();

    // ---- L2: h1(B) -> h2(A); x1 = maxk(h1)
    maxk<64, 72>(bufB, cat_ws, 0, t, b, n0);
    mfma_layer<4, 2, 72, 72>(bufB, bufA, wf2, wave, lane);
    __syncthreads();

    // ---- L3: h2(A) -> h3(B); x2 = maxk(h2)
    maxk<64, 72>(bufA, cat_ws, 64, t, b, n0);
    mfma_layer<8, 2, 72, 136>(bufA, bufB, wf3, wave, lane);
    __syncthreads();

    // ---- L4: h3(B) -> per-wave slab (A) -> relu+max -> cat; x3 = maxk(h3)
    maxk<128, 136>(bufB, cat_ws, 128, t, b, n0);
    {
        float* slab = (float*)bufA + wave * 1600;   // [80][20] f32, wave-private
        const int col = lane & 15, quad = lane >> 4;
        #pragma unroll
        for (int ni = 0; ni < 4; ++ni) {
            const int nt = wave * 4 + ni;
            short8 bfrag[4];
            #pragma unroll
            for (int k = 0; k < 4; ++k)
                bfrag[k] = *(const short8*)(wf4 + ((size_t)(nt * 4 + k) * 64 + lane) * 8);
            #pragma unroll
            for (int mt = 0; mt < 5; ++mt) {
                floatx4 acc = {0.f, 0.f, 0.f, 0.f};
                #pragma unroll
                for (int k = 0; k < 4; ++k) {
                    const short8 af = *(const short8*)(bufB + (mt * 16 + col) * 136
                                                           + k * 32 + quad * 8);
                    acc = __builtin_amdgcn_mfma_f32_16x16x32_bf16(af, bfrag[k], acc, 0, 0, 0);
                }
                #pragma unroll
                for (int r = 0; r < 4; ++r)
                    slab[(mt * 16 + quad * 4 + r) * 20 + col] = fmaxf(acc[r], 0.f);
            }
            const int p = lane >> 4, grp = (lane >> 2) & 3, kq = lane & 3;
            floatx4 mx = {0.f, 0.f, 0.f, 0.f};
            #pragma unroll
            for (int i = 0; i < 5; ++i) {
                const floatx4 v = *(const floatx4*)&slab[(p * KNN + kq * 5 + i) * 20 + grp * 4];
                mx[0] = fmaxf(mx[0], v[0]); mx[1] = fmaxf(mx[1], v[1]);
                mx[2] = fmaxf(mx[2], v[2]); mx[3] = fmaxf(mx[3], v[3]);
            }
            #pragma unroll
            for (int r = 0; r < 4; ++r) {
                mx[r] = fmaxf(mx[r], __shfl_xor(mx[r], 1));
                mx[r] = fmaxf(mx[r], __shfl_xor(mx[r], 2));
            }
            if (kq == 0) {
                ushort4v q;
                q.x = f2bf(mx[0]); q.y = f2bf(mx[1]);
                q.z = f2bf(mx[2]); q.w = f2bf(mx[3]);
                uint16_t* dst = cat_ws + ((size_t)b * NPTS + n0 + p) * 512
                              + 256 + nt * 16 + grp * 4;
                *(ushort4v*)dst = q;
            }
        }
    }
}

// ---------------------------------------------------------------------------
// Final GEMM, MFMA: out[b,o,n] = relu( sum_c w5[o,c] * cat[b,n,c] ).
// 64(o) x 64(n) tile, 4 waves (wave = o-subtile), K-chunks of 64.
__global__ __launch_bounds__(256) void final_gemm_mfma(
    const uint16_t* __restrict__ w5b,  // (512,512) bf16 row-major (o,c)
    const uint16_t* __restrict__ cat,  // (B*N,512) bf16
    float* __restrict__ out)           // (B,512,N) f32
{
    const int b  = blockIdx.z;
    const int o0 = blockIdx.y * 64;
    const int n0 = blockIdx.x * 64;
    const int t  = threadIdx.x;
    const int wave = t >> 6, lane = t & 63;
    const int col = lane & 15, quad = lane >> 4;

    __shared__ __align__(16) uint16_t As[64 * 72];  // w5 tile [o][k], +8 pad
    __shared__ __align__(16) uint16_t Bs[64 * 72];  // cat tile [n][k], +8 pad

    floatx4 acc[4] = {{0.f,0.f,0.f,0.f},{0.f,0.f,0.f,0.f},
                      {0.f,0.f,0.f,0.f},{0.f,0.f,0.f,0.f}};

    const size_t arow_base = (size_t)o0 * 512;
    const size_t brow_base = ((size_t)b * NPTS + n0) * 512;

    for (int kc = 0; kc < 512; kc += 64) {
        #pragma unroll
        for (int i = 0; i < 2; ++i) {
            const int idx = t + i * 256;          // 0..511
            const int row = idx >> 3;             // 0..63
            const int k8  = (idx & 7) * 8;        // 0..56
            *(short8*)&As[row * 72 + k8] =
                *(const short8*)&w5b[arow_base + (size_t)row * 512 + kc + k8];
            *(short8*)&Bs[row * 72 + k8] =
                *(const short8*)&cat[brow_base + (size_t)row * 512 + kc + k8];
        }
        __syncthreads();
        #pragma unroll
        for (int kt = 0; kt < 2; ++kt) {
            const short8 af = *(const short8*)&As[(wave * 16 + col) * 72 + kt * 32 + quad * 8];
            #pragma unroll
            for (int ns = 0; ns < 4; ++ns) {
                const short8 bf = *(const short8*)&Bs[(ns * 16 + col) * 72 + kt * 32 + quad * 8];
                acc[ns] = __builtin_amdgcn_mfma_f32_16x16x32_bf16(af, bf, acc[ns], 0, 0, 0);
            }
        }
        __syncthreads();
    }

    #pragma unroll
    for (int ns = 0; ns < 4; ++ns) {
        #pragma unroll
        for (int r = 0; r < 4; ++r) {
            out[((size_t)b * 512 + o0 + wave * 16 + quad * 4 + r) * NPTS
                + n0 + ns * 16 + col] = fmaxf(acc[ns][r], 0.f);
        }
    }
}

// ---------------------------------------------------------------------------
extern "C" void kernel_launch(void* const* d_in, const int* in_sizes, int n_in,
                              void* d_out, int out_size, void* d_ws, size_t ws_size,
                              hipStream_t stream) {
    const float* x  = (const float*)d_in[0];  // (8,3,4096)
    const float* w1 = (const float*)d_in[1];  // (64,26)
    const float* w2 = (const float*)d_in[2];  // (64,64)
    const float* w3 = (const float*)d_in[3];  // (128,64)
    const float* w4 = (const float*)d_in[4];  // (256,128)
    const float* w5 = (const float*)d_in[5];  // (512,512)
    float* out = (float*)d_out;               // (8,512,4096) fp32

    // workspace layout (bytes):
    //   [0)         idx_ws   B*N*K int     = 2,621,440
    //   [2621440)   dist_ws  B*N*K f32     = 2,621,440
    //   [5242880)   cat_ws   B*N*512 bf16  = 33,554,432
    //               (xyzs aliases cat_ws[0:512KB]: consumed by topk BEFORE
    //                fused_mlp writes cat — stream-ordered, safe)
    //   [38797312)  w5b bf16 (512x512)     = 524,288
    //   [72351744)  wf1 4 KB; wf2 8 KB; wf3 16 KB; wf4 64 KB
    char* ws = (char*)d_ws;
    int*      idx_ws  = (int*)ws;
    float*    dist_ws = (float*)(ws + 2621440);
    uint16_t* cat_ws  = (uint16_t*)(ws + 5242880);
    float4*   xyzs    = (float4*)(ws + 5242880);   // alias, 512 KB
    uint16_t* w5b     = (uint16_t*)(ws + 38797312);
    uint16_t* wf1     = (uint16_t*)(ws + 72351744);
    uint16_t* wf2     = (uint16_t*)(ws + 72351744 + 4096);
    uint16_t* wf3     = (uint16_t*)(ws + 72351744 + 4096 + 8192);
    uint16_t* wf4     = (uint16_t*)(ws + 72351744 + 4096 + 8192 + 16384);

    prep_wfrag<<<dim3(1), 256, 0, stream>>>(w1, wf1, 26,  4, 1);
    prep_wfrag<<<dim3(2), 256, 0, stream>>>(w2, wf2, 64,  4, 2);
    prep_wfrag<<<dim3(4), 256, 0, stream>>>(w3, wf3, 64,  8, 2);
    prep_wfrag<<<dim3(16), 256, 0, stream>>>(w4, wf4, 128, 16, 4);
    prep_w5bf<<<dim3(1024), 256, 0, stream>>>(w5, w5b);
    prep_xyzs<<<dim3((NB * NPTS + 255) / 256), 256, 0, stream>>>(x, xyzs);

    topk_kernel<<<dim3(NPTS / 4, NB), 256, 0, stream>>>(xyzs, idx_ws, dist_ws);
    fused_mlp_mfma<<<dim3(NPTS / P, NB), 256, 0, stream>>>(
        x, idx_ws, dist_ws, wf1, wf2, wf3, wf4, cat_ws);
    final_gemm_mfma<<<dim3(NPTS / 64, 512 / 64, NB), 256, 0, stream>>>(w5b, cat_ws, out);
}